// Round 7
// baseline (1194.469 us; speedup 1.0000x reference)
//
#include <hip/hip_runtime.h>
#include <math.h>

#define NTREE 512
#define NNODE 48
#define HD 256
#define LD 64
#define VOC 800
#define TSTEP 94
#define NFWD 47

typedef __attribute__((ext_vector_type(8))) short s8v;   // 8 bf16 (4 VGPRs)
typedef __attribute__((ext_vector_type(4))) float f4v;   // 4 fp32 acc

__device__ __forceinline__ float sigm(float x) { return 1.f / (1.f + expf(-x)); }

__device__ __forceinline__ float bfu(unsigned short u) {
    union { unsigned int i; float f; } c; c.i = ((unsigned int)u) << 16; return c.f;
}
__device__ __forceinline__ unsigned short f2bf(float f) {
    union { float f; unsigned int u; } c; c.f = f;
    return (unsigned short)((c.u + 0x7fffu + ((c.u >> 16) & 1u)) >> 16);
}
__device__ __forceinline__ s8v frag(const unsigned short* p) {
    union { int4 i; s8v v; } u; u.i = *(const int4*)p; return u.v;
}
__device__ __forceinline__ s8v zfrag() {
    union { int4 i; s8v v; } u; u.i = make_int4(0, 0, 0, 0); return u.v;
}
// LDS-only barrier: global ops (hsb stores, gathers) stay in flight.
__device__ __forceinline__ void bar_lgkm() {
    asm volatile("s_waitcnt lgkmcnt(0)\n\ts_barrier" ::: "memory");
}

// ---------------------------------------------------------------------------
// Precompute x-projections for all 800 vocab words (biases folded in).
// ---------------------------------------------------------------------------
#define PV 8
__global__ __launch_bounds__(256) void prep_xproj(
    const float* __restrict__ emb,
    const float* __restrict__ Wz, const float* __restrict__ bz,
    const float* __restrict__ Wh, const float* __restrict__ bh,
    const float* __restrict__ Wr, const float* __restrict__ br,
    float* __restrict__ xzT, float* __restrict__ xhT, float* __restrict__ xrT)
{
    __shared__ float embL[PV][HD];
    const int j = threadIdx.x;
    const int v0 = blockIdx.x * PV;
    for (int r = 0; r < PV; ++r) embL[r][j] = emb[(v0 + r) * HD + j];
    __syncthreads();

    float az[PV], ah[PV], ar[PV];
#pragma unroll
    for (int r = 0; r < PV; ++r) { az[r] = bz[j]; ah[r] = bh[j]; ar[r] = br[j]; }
    for (int i = 0; i < HD; i += 4) {
        float wz0 = Wz[(i + 0) * HD + j], wz1 = Wz[(i + 1) * HD + j];
        float wz2 = Wz[(i + 2) * HD + j], wz3 = Wz[(i + 3) * HD + j];
        float wh0 = Wh[(i + 0) * HD + j], wh1 = Wh[(i + 1) * HD + j];
        float wh2 = Wh[(i + 2) * HD + j], wh3 = Wh[(i + 3) * HD + j];
        float wr0 = Wr[(i + 0) * HD + j], wr1 = Wr[(i + 1) * HD + j];
        float wr2 = Wr[(i + 2) * HD + j], wr3 = Wr[(i + 3) * HD + j];
#pragma unroll
        for (int r = 0; r < PV; ++r) {
            float4 e = *(const float4*)&embL[r][i];
            az[r] += e.x * wz0 + e.y * wz1 + e.z * wz2 + e.w * wz3;
            ah[r] += e.x * wh0 + e.y * wh1 + e.z * wh2 + e.w * wh3;
            ar[r] += e.x * wr0 + e.y * wr1 + e.z * wr2 + e.w * wr3;
        }
    }
#pragma unroll
    for (int r = 0; r < PV; ++r) {
        xzT[(v0 + r) * HD + j] = az[r];
        xhT[(v0 + r) * HD + j] = ah[r];
        xrT[(v0 + r) * HD + j] = ar[r];
    }
}

// Fused transpose-convert for the three 256x256 GRU matrices.
__global__ __launch_bounds__(256) void tcvt3(
    const float* __restrict__ Wz, const float* __restrict__ Wh,
    const float* __restrict__ Ur,
    unsigned short* __restrict__ WzT, unsigned short* __restrict__ WhT,
    unsigned short* __restrict__ UrT)
{
    const int which = blockIdx.x >> 8, n = blockIdx.x & 255, k = threadIdx.x;
    const float* src = (which == 0) ? (Wz + HD * HD) : (which == 1) ? (Wh + HD * HD) : Ur;
    unsigned short* dst = (which == 0) ? WzT : (which == 1) ? WhT : UrT;
    dst[n * HD + k] = f2bf(src[k * HD + n]);
}

// Fused transpose-convert for head matrices: W1T[256][320], WoT[800][256], UwT[256][576].
__global__ __launch_bounds__(256) void tcvtQ(
    const float* __restrict__ Ww, const float* __restrict__ Wow,
    const float* __restrict__ Uw,
    unsigned short* __restrict__ W1T, unsigned short* __restrict__ WoT,
    unsigned short* __restrict__ UwT)
{
    int b = blockIdx.x;
    if (b < 256) {
        for (int k = threadIdx.x; k < 320; k += 256)
            W1T[b * 320 + k] = f2bf(Ww[k * 256 + b]);
    } else if (b < 1056) {
        int n = b - 256;
        WoT[n * 256 + threadIdx.x] = f2bf(Wow[threadIdx.x * VOC + n]);
    } else {
        int n = b - 1056;
        for (int k = threadIdx.x; k < 576; k += 256)
            UwT[n * 576 + k] = f2bf(Uw[k * 256 + n]);
    }
}

// Fused bf16 casts: embB (800*256) then tvB (512*64).
__global__ __launch_bounds__(256) void cvtE(
    const float* __restrict__ emb, const float* __restrict__ tv,
    unsigned short* __restrict__ embB, unsigned short* __restrict__ tvB)
{
    int idx = blockIdx.x * 256 + threadIdx.x;
    if (idx < VOC * HD) embB[idx] = f2bf(emb[idx]);
    else {
        int i2 = idx - VOC * HD;
        if (i2 < NTREE * LD) tvB[i2] = f2bf(tv[i2]);
    }
}

// ---------------------------------------------------------------------------
// GRU v6: 64 wgs x 256 thr (4 waves), 8 trees/wg, launch_bounds(256,1) so the
// full 512 unified VGPR+AGPR budget is available. Each wave owns 4 n-tiles of
// Wz/Wh/Ur (96 B-frags in regs/AGPRs, loaded once). A (mB/armB) in LDS
// fragment-contiguous [kt][lane][8] with (ln<8)-guarded reads. Finalize is
// in-register on lq<2 lanes (C rows 0-7). 2 LDS-only barriers/step.
// ---------------------------------------------------------------------------
__global__ __launch_bounds__(256, 1) void gru6(
    const int* __restrict__ wid,
    const float* __restrict__ xzT, const float* __restrict__ xhT,
    const float* __restrict__ xrT,
    const unsigned short* __restrict__ WzT, const unsigned short* __restrict__ WhT,
    const unsigned short* __restrict__ UrT,
    unsigned short* __restrict__ hsb)
{
    __shared__ unsigned short mBL[2][8 * 64 * 8];    // 8 KB each buffer
    __shared__ unsigned short armBL[2][8 * 64 * 8];
    __shared__ int widL[8][NNODE];

    const int tid = threadIdx.x;
    const int wave = tid >> 6, lane = tid & 63;
    const int lq = lane >> 4, ln = lane & 15;
    const int b0 = blockIdx.x * 8;
    const bool fin = (lq < 2);

    for (int i = tid; i < 8 * NNODE; i += 256)
        widL[i / NNODE][i % NNODE] = wid[(b0 + i / NNODE) * NNODE + (i % NNODE)];

    // loop-invariant weight fragments: 4 n-tiles x 3 matrices x 8 k-frags
    s8v wz[4][8], wh[4][8], wu[4][8];
#pragma unroll
    for (int tt = 0; tt < 4; ++tt) {
        const int n = wave * 64 + tt * 16 + ln;
#pragma unroll
        for (int kt = 0; kt < 8; ++kt) {
            const int ko = kt * 32 + lq * 8;
            wz[tt][kt] = frag(&WzT[n * HD + ko]);
            wh[tt][kt] = frag(&WhT[n * HD + ko]);
            wu[tt][kt] = frag(&UrT[n * HD + ko]);
        }
    }
    __syncthreads();

    float mF[4][4];   // persistent m_e for finalize lanes

    for (int t = 0; t < TSTEP; ++t) {
        const int par = t & 1, nxt = par ^ 1;
        const bool fwd = t < NFWD;
        const int u = TSTEP - t;
        const int src = fwd ? t : u;
        const int dst = fwd ? (t + 1) : (u - 1);
        const bool hp = (t != 0) && (t != NFWD);

        // ---- issue xz/xh gathers now (consumed after phase-A MFMA) ----
        float xzv[4][4], xhv[4][4];
        if (fin) {
#pragma unroll
            for (int tt = 0; tt < 4; ++tt)
#pragma unroll
                for (int r = 0; r < 4; ++r) {
                    const int m = lq * 4 + r;
                    const int n = wave * 64 + tt * 16 + ln;
                    const int ws = widL[m][src];
                    xzv[tt][r] = xzT[ws * HD + n];
                    xhv[tt][r] = xhT[ws * HD + n];
                }
        }

        // ---- phase A MFMA: az, ah ----
        f4v cz[4], ch[4];
#pragma unroll
        for (int tt = 0; tt < 4; ++tt) { cz[tt] = (f4v){0.f,0.f,0.f,0.f}; ch[tt] = cz[tt]; }
        if (hp) {
#pragma unroll
            for (int kt = 0; kt < 8; ++kt) {
                s8v am = (ln < 8) ? frag(&mBL[par][(kt * 64 + lane) * 8]) : zfrag();
                s8v aa = (ln < 8) ? frag(&armBL[par][(kt * 64 + lane) * 8]) : zfrag();
#pragma unroll
                for (int tt = 0; tt < 4; ++tt) {
                    cz[tt] = __builtin_amdgcn_mfma_f32_16x16x32_bf16(am, wz[tt][kt], cz[tt], 0, 0, 0);
                    ch[tt] = __builtin_amdgcn_mfma_f32_16x16x32_bf16(aa, wh[tt][kt], ch[tt], 0, 0, 0);
                }
            }
        }

        // ---- issue xr gathers (consumed at finalize-B) ----
        float xrv[4][4];
        if (fin) {
#pragma unroll
            for (int tt = 0; tt < 4; ++tt)
#pragma unroll
                for (int r = 0; r < 4; ++r) {
                    const int m = lq * 4 + r;
                    const int n = wave * 64 + tt * 16 + ln;
                    xrv[tt][r] = xrT[widL[m][dst] * HD + n];
                }
        }

        // ---- finalize A: z, mt, m_e, h_v store (lq<2 lanes) ----
        if (fin) {
#pragma unroll
            for (int tt = 0; tt < 4; ++tt) {
                const int n = wave * 64 + tt * 16 + ln;
                const int kt_w = n >> 5, qq_w = (n >> 3) & 3, j_w = n & 7;
#pragma unroll
                for (int r = 0; r < 4; ++r) {
                    const int m = lq * 4 + r;
                    float az = xzv[tt][r], ah = xhv[tt][r], sold = 0.f;
                    if (hp) { az += cz[tt][r]; ah += ch[tt][r]; sold = mF[tt][r]; }
                    float z = sigm(az), mt = tanhf(ah);
                    float me = sold + z * (mt - sold);
                    float hv = me;
                    if (!fwd && dst > 0)
                        hv += bfu(hsb[((dst - 1) * NTREE + b0 + m) * HD + n]);
                    hsb[(t * NTREE + b0 + m) * HD + n] = f2bf(hv);
                    mF[tt][r] = me;
                    mBL[nxt][(kt_w * 64 + qq_w * 16 + m) * 8 + j_w] = f2bf(me);
                }
            }
        }
        bar_lgkm();

        // ---- phase B MFMA: ar = m_e @ Ur ----
        f4v cr[4];
#pragma unroll
        for (int tt = 0; tt < 4; ++tt) cr[tt] = (f4v){0.f,0.f,0.f,0.f};
#pragma unroll
        for (int kt = 0; kt < 8; ++kt) {
            s8v a = (ln < 8) ? frag(&mBL[nxt][(kt * 64 + lane) * 8]) : zfrag();
#pragma unroll
            for (int tt = 0; tt < 4; ++tt)
                cr[tt] = __builtin_amdgcn_mfma_f32_16x16x32_bf16(a, wu[tt][kt], cr[tt], 0, 0, 0);
        }

        // ---- finalize B: r, arm (lq<2 lanes) ----
        if (fin) {
#pragma unroll
            for (int tt = 0; tt < 4; ++tt) {
                const int n = wave * 64 + tt * 16 + ln;
                const int kt_w = n >> 5, qq_w = (n >> 3) & 3, j_w = n & 7;
#pragma unroll
                for (int r = 0; r < 4; ++r) {
                    const int m = lq * 4 + r;
                    float arm = sigm(xrv[tt][r] + cr[tt][r]) * mF[tt][r];
                    armBL[nxt][(kt_w * 64 + qq_w * 16 + m) * 8 + j_w] = f2bf(arm);
                }
            }
        }
        bar_lgkm();
    }
}

// ---------------------------------------------------------------------------
// Q head, MFMA. 768 wgs (48 trow x 16 tree-groups) x 256 thr. 32 rows/wg.
// ---------------------------------------------------------------------------
#define QG 32
__global__ __launch_bounds__(256) void q3(
    const int* __restrict__ wid,
    const unsigned short* __restrict__ tvB,
    const unsigned short* __restrict__ hsb,
    const unsigned short* __restrict__ W1T,
    const unsigned short* __restrict__ WoT,
    const float* __restrict__ Wb,
    const float* __restrict__ Wob,
    float* __restrict__ acc)
{
    __shared__ unsigned short X1L[QG][328];
    __shared__ unsigned short hidL[QG][264];
    __shared__ int tgts[QG];
    __shared__ float wred[4][QG][4];
    const int tid = threadIdx.x;
    const int wave = tid >> 6, lane = tid & 63;
    const int lq = lane >> 4, ln = lane & 15;
    const int trow = blockIdx.x >> 4;
    const int b0 = (blockIdx.x & 15) * QG;

    if (tid < QG) tgts[tid] = wid[(b0 + tid) * NNODE + trow];
    if (trow == 0) {
        int4 z = make_int4(0, 0, 0, 0);
        for (int idx = tid; idx < QG * 32; idx += 256) {
            int m = idx >> 5, c = idx & 31;
            *(int4*)&X1L[m][c * 8] = z;
        }
    } else {
        const unsigned short* hrow = hsb + (size_t)(trow - 1) * NTREE * HD;
        for (int idx = tid; idx < QG * 32; idx += 256) {
            int m = idx >> 5, c = idx & 31;
            *(int4*)&X1L[m][c * 8] = *(const int4*)&hrow[(b0 + m) * HD + c * 8];
        }
    }
    for (int idx = tid; idx < QG * 8; idx += 256) {
        int m = idx >> 3, c = idx & 7;
        *(int4*)&X1L[m][256 + c * 8] = *(const int4*)&tvB[(b0 + m) * LD + c * 8];
    }
    __syncthreads();

    f4v acc1[2][4];
#pragma unroll
    for (int mt = 0; mt < 2; ++mt)
#pragma unroll
        for (int nt = 0; nt < 4; ++nt) acc1[mt][nt] = (f4v){0.f, 0.f, 0.f, 0.f};
#pragma unroll
    for (int kt = 0; kt < 10; ++kt) {
        s8v a0 = frag(&X1L[ln][kt * 32 + lq * 8]);
        s8v a1 = frag(&X1L[16 + ln][kt * 32 + lq * 8]);
#pragma unroll
        for (int nt = 0; nt < 4; ++nt) {
            int n = wave * 64 + nt * 16 + ln;
            s8v b = frag(&W1T[n * 320 + kt * 32 + lq * 8]);
            acc1[0][nt] = __builtin_amdgcn_mfma_f32_16x16x32_bf16(a0, b, acc1[0][nt], 0, 0, 0);
            acc1[1][nt] = __builtin_amdgcn_mfma_f32_16x16x32_bf16(a1, b, acc1[1][nt], 0, 0, 0);
        }
    }
#pragma unroll
    for (int nt = 0; nt < 4; ++nt) {
        int col = wave * 64 + nt * 16 + ln;
        float wb = Wb[col];
#pragma unroll
        for (int mt = 0; mt < 2; ++mt)
#pragma unroll
            for (int r = 0; r < 4; ++r)
                hidL[mt * 16 + lq * 4 + r][col] = f2bf(fmaxf(acc1[mt][nt][r] + wb, 0.f));
    }
    __syncthreads();

    int rt[2][4];
#pragma unroll
    for (int mt = 0; mt < 2; ++mt)
#pragma unroll
        for (int r = 0; r < 4; ++r) rt[mt][r] = tgts[mt * 16 + lq * 4 + r];
    float mx[2][4], ls[2][4], tg[2][4]; int am[2][4];
#pragma unroll
    for (int mt = 0; mt < 2; ++mt)
#pragma unroll
        for (int r = 0; r < 4; ++r) { mx[mt][r] = -1e30f; ls[mt][r] = 0.f; tg[mt][r] = 0.f; am[mt][r] = 1 << 30; }

    for (int nt = wave; nt < 50; nt += 4) {
        int n = nt * 16 + ln;
        const unsigned short* wrow = WoT + n * 256;
        f4v a2[2];
        a2[0] = (f4v){0.f, 0.f, 0.f, 0.f}; a2[1] = (f4v){0.f, 0.f, 0.f, 0.f};
#pragma unroll
        for (int kt = 0; kt < 8; ++kt) {
            s8v a0 = frag(&hidL[ln][kt * 32 + lq * 8]);
            s8v a1 = frag(&hidL[16 + ln][kt * 32 + lq * 8]);
            s8v b = frag(&wrow[kt * 32 + lq * 8]);
            a2[0] = __builtin_amdgcn_mfma_f32_16x16x32_bf16(a0, b, a2[0], 0, 0, 0);
            a2[1] = __builtin_amdgcn_mfma_f32_16x16x32_bf16(a1, b, a2[1], 0, 0, 0);
        }
        float bias = Wob[n];
#pragma unroll
        for (int mt = 0; mt < 2; ++mt)
#pragma unroll
            for (int r = 0; r < 4; ++r) {
                float v = a2[mt][r] + bias;
                if (n == rt[mt][r]) tg[mt][r] = v;
                float nm = fmaxf(mx[mt][r], v);
                ls[mt][r] = ls[mt][r] * __expf(mx[mt][r] - nm) + __expf(v - nm);
                if (v > mx[mt][r]) am[mt][r] = n;
                mx[mt][r] = nm;
            }
    }

#pragma unroll
    for (int s = 1; s < 16; s <<= 1) {
#pragma unroll
        for (int mt = 0; mt < 2; ++mt)
#pragma unroll
            for (int r = 0; r < 4; ++r) {
                float mo = __shfl_xor(mx[mt][r], s);
                float lo = __shfl_xor(ls[mt][r], s);
                int   ao = __shfl_xor(am[mt][r], s);
                float to = __shfl_xor(tg[mt][r], s);
                tg[mt][r] += to;
                float nm = fmaxf(mx[mt][r], mo);
                ls[mt][r] = ls[mt][r] * __expf(mx[mt][r] - nm) + lo * __expf(mo - nm);
                if (mo > mx[mt][r] || (mo == mx[mt][r] && ao < am[mt][r])) am[mt][r] = ao;
                mx[mt][r] = nm;
            }
    }
    if (ln == 0) {
#pragma unroll
        for (int mt = 0; mt < 2; ++mt)
#pragma unroll
            for (int r = 0; r < 4; ++r) {
                int row = mt * 16 + lq * 4 + r;
                wred[wave][row][0] = mx[mt][r];
                wred[wave][row][1] = ls[mt][r];
                wred[wave][row][2] = __int_as_float(am[mt][r]);
                wred[wave][row][3] = tg[mt][r];
            }
    }
    __syncthreads();

    float lossv = 0.f, corrv = 0.f;
    if (tid < QG) {
        float m_ = -1e30f, l_ = 0.f, t_ = 0.f; int a_ = 1 << 30;
#pragma unroll
        for (int w = 0; w < 4; ++w) {
            float mo = wred[w][tid][0], lo = wred[w][tid][1], to = wred[w][tid][3];
            int ao = __float_as_int(wred[w][tid][2]);
            t_ += to;
            float nm = fmaxf(m_, mo);
            l_ = l_ * __expf(m_ - nm) + lo * __expf(mo - nm);
            if (mo > m_ || (mo == m_ && ao < a_)) a_ = ao;
            m_ = nm;
        }
        lossv = m_ + logf(l_) - t_;
        corrv = (a_ == tgts[tid]) ? 1.f : 0.f;
    }
    if (wave == 0) {
        for (int s = 32; s; s >>= 1) {
            lossv += __shfl_down(lossv, s);
            corrv += __shfl_down(corrv, s);
        }
        if (tid == 0) {
            int slot = blockIdx.x & 255;
            atomicAdd(&acc[0 * 256 + slot], lossv);
            atomicAdd(&acc[2 * 256 + slot], corrv);
        }
    }
}

// ---------------------------------------------------------------------------
// P head, MFMA. 1520 wgs (95 trow x 16 groups) x 256 thr. 32 rows/wg.
// ---------------------------------------------------------------------------
#define PG 32
__global__ __launch_bounds__(256) void p3(
    const int* __restrict__ wid,
    const unsigned short* __restrict__ tvB,
    const unsigned short* __restrict__ embB,
    const unsigned short* __restrict__ hsb,
    const unsigned short* __restrict__ UwT,
    const float* __restrict__ Ub,
    const float* __restrict__ Usw, const float* __restrict__ Usb,
    float* __restrict__ acc)
{
    __shared__ unsigned short XL[PG][584];
    __shared__ int widL[PG];
    __shared__ float wredp[4][PG];
    const int tid = threadIdx.x;
    const int wave = tid >> 6, lane = tid & 63;
    const int lq = lane >> 4, ln = lane & 15;
    const int trow = blockIdx.x >> 4;
    const int b0 = (blockIdx.x & 15) * PG;
    const int node = (trow == 0) ? 0 : ((trow <= NFWD) ? trow : (TSTEP - trow));

    if (tid < PG) widL[tid] = wid[(b0 + tid) * NNODE + node];
    __syncthreads();

    for (int idx = tid; idx < PG * 32; idx += 256) {
        int m = idx >> 5, c = idx & 31;
        *(int4*)&XL[m][c * 8] = *(const int4*)&embB[widL[m] * HD + c * 8];
    }
    if (trow == 0) {
        int4 z = make_int4(0, 0, 0, 0);
        for (int idx = tid; idx < PG * 32; idx += 256) {
            int m = idx >> 5, c = idx & 31;
            *(int4*)&XL[m][256 + c * 8] = z;
        }
    } else {
        const unsigned short* hrow = hsb + (size_t)(trow - 1) * NTREE * HD;
        for (int idx = tid; idx < PG * 32; idx += 256) {
            int m = idx >> 5, c = idx & 31;
            *(int4*)&XL[m][256 + c * 8] = *(const int4*)&hrow[(b0 + m) * HD + c * 8];
        }
    }
    for (int idx = tid; idx < PG * 8; idx += 256) {
        int m = idx >> 3, c = idx & 7;
        *(int4*)&XL[m][512 + c * 8] = *(const int4*)&tvB[(b0 + m) * LD + c * 8];
    }
    __syncthreads();

    f4v a1[2][4];
#pragma unroll
    for (int mt = 0; mt < 2; ++mt)
#pragma unroll
        for (int nt = 0; nt < 4; ++nt) a1[mt][nt] = (f4v){0.f, 0.f, 0.f, 0.f};
    for (int kt = 0; kt < 18; ++kt) {
        s8v a0 = frag(&XL[ln][kt * 32 + lq * 8]);
        s8v am_ = frag(&XL[16 + ln][kt * 32 + lq * 8]);
#pragma unroll
        for (int nt = 0; nt < 4; ++nt) {
            int n = wave * 64 + nt * 16 + ln;
            s8v b = frag(&UwT[n * 576 + kt * 32 + lq * 8]);
            a1[0][nt] = __builtin_amdgcn_mfma_f32_16x16x32_bf16(a0, b, a1[0][nt], 0, 0, 0);
            a1[1][nt] = __builtin_amdgcn_mfma_f32_16x16x32_bf16(am_, b, a1[1][nt], 0, 0, 0);
        }
    }
    float part[2][4] = {{0, 0, 0, 0}, {0, 0, 0, 0}};
#pragma unroll
    for (int nt = 0; nt < 4; ++nt) {
        int n = wave * 64 + nt * 16 + ln;
        float ub = Ub[n], us = Usw[n];
#pragma unroll
        for (int mt = 0; mt < 2; ++mt)
#pragma unroll
            for (int r = 0; r < 4; ++r)
                part[mt][r] += fmaxf(a1[mt][nt][r] + ub, 0.f) * us;
    }
#pragma unroll
    for (int s = 1; s < 16; s <<= 1) {
#pragma unroll
        for (int mt = 0; mt < 2; ++mt)
#pragma unroll
            for (int r = 0; r < 4; ++r)
                part[mt][r] += __shfl_xor(part[mt][r], s);
    }
    if (ln == 0) {
#pragma unroll
        for (int mt = 0; mt < 2; ++mt)
#pragma unroll
            for (int r = 0; r < 4; ++r)
                wredp[wave][mt * 16 + lq * 4 + r] = part[mt][r];
    }
    __syncthreads();

    float lossv = 0.f, corrv = 0.f;
    if (tid < PG) {
        float p = wredp[0][tid] + wredp[1][tid] + wredp[2][tid] + wredp[3][tid] + Usb[0];
        float tgt = (trow < NFWD) ? 1.f : 0.f;
        lossv = fmaxf(p, 0.f) - p * tgt + log1pf(expf(-fabsf(p)));
        corrv = (((p > 0.f) ? 1 : 0) == ((trow < NFWD) ? 1 : 0)) ? 1.f : 0.f;
    }
    if (wave == 0) {
        for (int s = 32; s; s >>= 1) {
            lossv += __shfl_down(lossv, s);
            corrv += __shfl_down(corrv, s);
        }
        if (tid == 0) {
            int slot = blockIdx.x & 255;
            atomicAdd(&acc[1 * 256 + slot], lossv);
            atomicAdd(&acc[3 * 256 + slot], corrv);
        }
    }
}

__global__ void init_kernel(float* __restrict__ acc) {
    acc[threadIdx.x] = 0.f;   // 1024 slots
}

__global__ void fin_kernel(const float* __restrict__ acc, float* __restrict__ out) {
    const int tid = threadIdx.x;
    const int c = tid >> 6, lane = tid & 63;
    float v = 0.f;
    for (int i = lane; i < 256; i += 64) v += acc[c * 256 + i];
    for (int s = 32; s; s >>= 1) v += __shfl_down(v, s);
    if (lane == 0) {
        const float sc[4] = {1.f / 512.f, 1.f / 512.f, 1.f / 24576.f, 1.f / 48640.f};
        out[c] = v * sc[c];
    }
}

extern "C" void kernel_launch(void* const* d_in, const int* in_sizes, int n_in,
                              void* d_out, int out_size, void* d_ws, size_t ws_size,
                              hipStream_t stream) {
    const int*   wid  = (const int*)  d_in[12];
    const float* tv   = (const float*)d_in[13];
    const float* emb  = (const float*)d_in[14];
    const float* Wz   = (const float*)d_in[15];
    const float* bz   = (const float*)d_in[16];
    const float* Wr   = (const float*)d_in[17];
    const float* Ur   = (const float*)d_in[18];
    const float* br   = (const float*)d_in[19];
    const float* Wh   = (const float*)d_in[20];
    const float* bh   = (const float*)d_in[21];
    const float* Ww   = (const float*)d_in[22];
    const float* Wb   = (const float*)d_in[23];
    const float* Uw   = (const float*)d_in[24];
    const float* Ubias= (const float*)d_in[25];
    const float* Wow  = (const float*)d_in[26];
    const float* Wob  = (const float*)d_in[27];
    const float* Usw  = (const float*)d_in[28];
    const float* Usb  = (const float*)d_in[29];

    char* w = (char*)d_ws;
    float* accb = (float*)w;                                 // 4 KB
    float* xzT  = (float*)(w + 4096);                        // 800*256 f32
    float* xhT  = (float*)(w + 823296);
    float* xrT  = (float*)(w + 1642496);
    unsigned short* WzT2 = (unsigned short*)(w + 2461696);   // [256 n][256 k] bf16
    unsigned short* WhT2 = (unsigned short*)(w + 2592768);
    unsigned short* UrT2 = (unsigned short*)(w + 2723840);
    unsigned short* hsb  = (unsigned short*)(w + 2854912);   // 94*512*256 bf16
    unsigned short* W1T  = (unsigned short*)(w + 27496448);  // [256][320]
    unsigned short* WoT  = (unsigned short*)(w + 27660288);  // [800][256]
    unsigned short* UwT  = (unsigned short*)(w + 28069888);  // [256][576]
    unsigned short* embB = (unsigned short*)(w + 28364800);  // [800][256]
    unsigned short* tvB  = (unsigned short*)(w + 28774400);  // [512][64]

    init_kernel<<<1, 1024, 0, stream>>>(accb);
    prep_xproj<<<VOC / PV, 256, 0, stream>>>(emb, Wz, bz, Wh, bh, Wr, br, xzT, xhT, xrT);
    tcvt3<<<768, 256, 0, stream>>>(Wz, Wh, Ur, WzT2, WhT2, UrT2);
    tcvtQ<<<1312, 256, 0, stream>>>(Ww, Wow, Uw, W1T, WoT, UwT);
    cvtE<<<(VOC * HD + NTREE * LD + 255) / 256, 256, 0, stream>>>(emb, tv, embB, tvB);
    gru6<<<NTREE / 8, 256, 0, stream>>>(wid, xzT, xhT, xrT, WzT2, WhT2, UrT2, hsb);
    q3<<<48 * 16, 256, 0, stream>>>(wid, tvB, hsb, W1T, WoT, Wb, Wob, accb);
    p3<<<95 * 16, 256, 0, stream>>>(wid, tvB, embB, hsb, UwT, Ubias, Usw, Usb, accb);
    fin_kernel<<<1, 256, 0, stream>>>(accb, (float*)d_out);
}

// Round 8
// 567.323 us; speedup vs baseline: 2.1054x; 2.1054x over previous
//
#include <hip/hip_runtime.h>
#include <math.h>

#define NTREE 512
#define NNODE 48
#define HD 256
#define LD 64
#define VOC 800
#define TSTEP 94
#define NFWD 47

typedef __attribute__((ext_vector_type(8))) short s8v;   // 8 bf16 (4 VGPRs)
typedef __attribute__((ext_vector_type(4))) float f4v;   // 4 fp32 acc

__device__ __forceinline__ float sigm(float x) { return 1.f / (1.f + expf(-x)); }

__device__ __forceinline__ float bfu(unsigned short u) {
    union { unsigned int i; float f; } c; c.i = ((unsigned int)u) << 16; return c.f;
}
__device__ __forceinline__ unsigned short f2bf(float f) {
    union { float f; unsigned int u; } c; c.f = f;
    return (unsigned short)((c.u + 0x7fffu + ((c.u >> 16) & 1u)) >> 16);
}
__device__ __forceinline__ s8v frag(const unsigned short* p) {
    union { int4 i; s8v v; } u; u.i = *(const int4*)p; return u.v;
}
__device__ __forceinline__ s8v zfrag() {
    union { int4 i; s8v v; } u; u.i = make_int4(0, 0, 0, 0); return u.v;
}
// LDS-only barrier: global ops (hsb stores, gathers) stay in flight.
__device__ __forceinline__ void bar_lgkm() {
    asm volatile("s_waitcnt lgkmcnt(0)\n\ts_barrier" ::: "memory");
}

// ---------------------------------------------------------------------------
// Precompute x-projections for all 800 vocab words (biases folded in).
// ---------------------------------------------------------------------------
#define PV 8
__global__ __launch_bounds__(256) void prep_xproj(
    const float* __restrict__ emb,
    const float* __restrict__ Wz, const float* __restrict__ bz,
    const float* __restrict__ Wh, const float* __restrict__ bh,
    const float* __restrict__ Wr, const float* __restrict__ br,
    float* __restrict__ xzT, float* __restrict__ xhT, float* __restrict__ xrT)
{
    __shared__ float embL[PV][HD];
    const int j = threadIdx.x;
    const int v0 = blockIdx.x * PV;
    for (int r = 0; r < PV; ++r) embL[r][j] = emb[(v0 + r) * HD + j];
    __syncthreads();

    float az[PV], ah[PV], ar[PV];
#pragma unroll
    for (int r = 0; r < PV; ++r) { az[r] = bz[j]; ah[r] = bh[j]; ar[r] = br[j]; }
    for (int i = 0; i < HD; i += 4) {
        float wz0 = Wz[(i + 0) * HD + j], wz1 = Wz[(i + 1) * HD + j];
        float wz2 = Wz[(i + 2) * HD + j], wz3 = Wz[(i + 3) * HD + j];
        float wh0 = Wh[(i + 0) * HD + j], wh1 = Wh[(i + 1) * HD + j];
        float wh2 = Wh[(i + 2) * HD + j], wh3 = Wh[(i + 3) * HD + j];
        float wr0 = Wr[(i + 0) * HD + j], wr1 = Wr[(i + 1) * HD + j];
        float wr2 = Wr[(i + 2) * HD + j], wr3 = Wr[(i + 3) * HD + j];
#pragma unroll
        for (int r = 0; r < PV; ++r) {
            float4 e = *(const float4*)&embL[r][i];
            az[r] += e.x * wz0 + e.y * wz1 + e.z * wz2 + e.w * wz3;
            ah[r] += e.x * wh0 + e.y * wh1 + e.z * wh2 + e.w * wh3;
            ar[r] += e.x * wr0 + e.y * wr1 + e.z * wr2 + e.w * wr3;
        }
    }
#pragma unroll
    for (int r = 0; r < PV; ++r) {
        xzT[(v0 + r) * HD + j] = az[r];
        xhT[(v0 + r) * HD + j] = ah[r];
        xrT[(v0 + r) * HD + j] = ar[r];
    }
}

// Fused transpose-convert for the three 256x256 GRU matrices.
__global__ __launch_bounds__(256) void tcvt3(
    const float* __restrict__ Wz, const float* __restrict__ Wh,
    const float* __restrict__ Ur,
    unsigned short* __restrict__ WzT, unsigned short* __restrict__ WhT,
    unsigned short* __restrict__ UrT)
{
    const int which = blockIdx.x >> 8, n = blockIdx.x & 255, k = threadIdx.x;
    const float* src = (which == 0) ? (Wz + HD * HD) : (which == 1) ? (Wh + HD * HD) : Ur;
    unsigned short* dst = (which == 0) ? WzT : (which == 1) ? WhT : UrT;
    dst[n * HD + k] = f2bf(src[k * HD + n]);
}

// Fused transpose-convert for head matrices: W1T[256][320], WoT[800][256], UwT[256][576].
__global__ __launch_bounds__(256) void tcvtQ(
    const float* __restrict__ Ww, const float* __restrict__ Wow,
    const float* __restrict__ Uw,
    unsigned short* __restrict__ W1T, unsigned short* __restrict__ WoT,
    unsigned short* __restrict__ UwT)
{
    int b = blockIdx.x;
    if (b < 256) {
        for (int k = threadIdx.x; k < 320; k += 256)
            W1T[b * 320 + k] = f2bf(Ww[k * 256 + b]);
    } else if (b < 1056) {
        int n = b - 256;
        WoT[n * 256 + threadIdx.x] = f2bf(Wow[threadIdx.x * VOC + n]);
    } else {
        int n = b - 1056;
        for (int k = threadIdx.x; k < 576; k += 256)
            UwT[n * 576 + k] = f2bf(Uw[k * 256 + n]);
    }
}

// Fused bf16 casts: embB (800*256) then tvB (512*64).
__global__ __launch_bounds__(256) void cvtE(
    const float* __restrict__ emb, const float* __restrict__ tv,
    unsigned short* __restrict__ embB, unsigned short* __restrict__ tvB)
{
    int idx = blockIdx.x * 256 + threadIdx.x;
    if (idx < VOC * HD) embB[idx] = f2bf(emb[idx]);
    else {
        int i2 = idx - VOC * HD;
        if (i2 < NTREE * LD) tvB[i2] = f2bf(tv[i2]);
    }
}

// ---------------------------------------------------------------------------
// GRU v7 = gru5 structure + gru4 register budget. 256 wgs x 512 thr (8 waves),
// 2 trees/wg, launch_bounds(512,2) -> 256 unified regs/wave. Wave w owns
// col-tiles 2w,2w+1 of Wz and Wh IN REGISTERS (32 frags = 128 regs); Ur lives
// in LDS fragment-contiguous (128 KB, loaded once, conflict-free b128 reads).
// In-register finalize on lq==0 lanes (C rows 0,1 = the 2 trees). 2 LDS-only
// barriers/step; per-lane gather prefetch one step ahead.
// ---------------------------------------------------------------------------
__global__ __launch_bounds__(512, 2) void gru7(
    const int* __restrict__ wid,
    const float* __restrict__ xzT, const float* __restrict__ xhT,
    const float* __restrict__ xrT,
    const unsigned short* __restrict__ WzT, const unsigned short* __restrict__ WhT,
    const unsigned short* __restrict__ UrT,
    unsigned short* __restrict__ hsb)
{
    __shared__ unsigned short urL[16 * 8 * 64 * 8];   // 128 KB [tile][kt][lane][8]
    __shared__ unsigned short mBL[2][2][HD], armBL[2][2][HD];
    __shared__ int widL[2][NNODE];

    const int tid = threadIdx.x;
    const int wave = tid >> 6, lane = tid & 63;
    const int lq = lane >> 4, ln = lane & 15;
    const int b0 = blockIdx.x * 2;
    const int T0 = 2 * wave, T1 = T0 + 1;
    const int c0 = wave * 32 + ln, c1 = c0 + 16;
    const bool owner = (lq == 0);

    if (tid < 2 * NNODE) widL[tid / NNODE][tid % NNODE] =
        wid[(b0 + tid / NNODE) * NNODE + (tid % NNODE)];

    // one-time: Ur -> LDS fragment-contiguous ([tile s][kt=wave][lane])
#pragma unroll
    for (int s = 0; s < 16; ++s) {
        *(int4*)&urL[((s * 8 + wave) * 64 + lane) * 8] =
            *(const int4*)&UrT[(s * 16 + ln) * HD + wave * 32 + lq * 8];
    }

    // loop-invariant phase-A weight fragments: 32 frags = 128 regs
    s8v wz0[8], wz1[8], wh0[8], wh1[8];
#pragma unroll
    for (int kt = 0; kt < 8; ++kt) {
        const int ko = kt * 32 + lq * 8;
        wz0[kt] = frag(&WzT[(T0 * 16 + ln) * HD + ko]);
        wz1[kt] = frag(&WzT[(T1 * 16 + ln) * HD + ko]);
        wh0[kt] = frag(&WhT[(T0 * 16 + ln) * HD + ko]);
        wh1[kt] = frag(&WhT[(T1 * 16 + ln) * HD + ko]);
    }
    __syncthreads();   // widL + urL visible

    float cxz[4], cxh[4], cxr[4], chsp[4], mF[4];
    float nxz[4], nxh[4], nxr[4], nhsp[4];

    if (owner) {       // prologue: gathers for t=0 (src=0, dst=1, fwd)
        const int ws0 = widL[0][0], ws1 = widL[1][0];
        const int wd0 = widL[0][1], wd1 = widL[1][1];
        cxz[0] = xzT[ws0 * HD + c0]; cxz[1] = xzT[ws0 * HD + c1];
        cxz[2] = xzT[ws1 * HD + c0]; cxz[3] = xzT[ws1 * HD + c1];
        cxh[0] = xhT[ws0 * HD + c0]; cxh[1] = xhT[ws0 * HD + c1];
        cxh[2] = xhT[ws1 * HD + c0]; cxh[3] = xhT[ws1 * HD + c1];
        cxr[0] = xrT[wd0 * HD + c0]; cxr[1] = xrT[wd0 * HD + c1];
        cxr[2] = xrT[wd1 * HD + c0]; cxr[3] = xrT[wd1 * HD + c1];
#pragma unroll
        for (int i = 0; i < 4; ++i) { chsp[i] = 0.f; mF[i] = 0.f; }
    }

#pragma unroll 2
    for (int t = 0; t < TSTEP; ++t) {
        const int par = t & 1, nxt = par ^ 1;
        const bool fwd = t < NFWD;
        const bool hp = (t != 0) && (t != NFWD);

        // ---- prefetch for t+1 (and t=47's own hsp) ----
        if (owner) {
            if (t == NFWD) {        // this step's hsp (row 45), written ~2 steps ago
#pragma unroll
                for (int i = 0; i < 4; ++i) {
                    int tree = i >> 1, c = (i & 1) ? c1 : c0;
                    chsp[i] = bfu(hsb[((NFWD - 2) * NTREE + b0 + tree) * HD + c]);
                }
            }
            const int tn = t + 1;
            if (tn < TSTEP) {
                const bool fwdn = tn < NFWD;
                const int un = TSTEP - tn;
                const int srcn = fwdn ? tn : un;
                const int dstn = fwdn ? (tn + 1) : (un - 1);
                const int ws0 = widL[0][srcn], ws1 = widL[1][srcn];
                const int wd0 = widL[0][dstn], wd1 = widL[1][dstn];
                nxz[0] = xzT[ws0 * HD + c0]; nxz[1] = xzT[ws0 * HD + c1];
                nxz[2] = xzT[ws1 * HD + c0]; nxz[3] = xzT[ws1 * HD + c1];
                nxh[0] = xhT[ws0 * HD + c0]; nxh[1] = xhT[ws0 * HD + c1];
                nxh[2] = xhT[ws1 * HD + c0]; nxh[3] = xhT[ws1 * HD + c1];
                nxr[0] = xrT[wd0 * HD + c0]; nxr[1] = xrT[wd0 * HD + c1];
                nxr[2] = xrT[wd1 * HD + c0]; nxr[3] = xrT[wd1 * HD + c1];
#pragma unroll
                for (int i = 0; i < 4; ++i) nhsp[i] = 0.f;
                if (tn > NFWD && dstn > 0) {   // row dstn-1 written >=3 steps ago
#pragma unroll
                    for (int i = 0; i < 4; ++i) {
                        int tree = i >> 1, c = (i & 1) ? c1 : c0;
                        nhsp[i] = bfu(hsb[((dstn - 1) * NTREE + b0 + tree) * HD + c]);
                    }
                }
            }
        }

        // ---- phase A MFMA: az, ah for own 2 tiles ----
        f4v cz0 = (f4v){0.f,0.f,0.f,0.f}, cz1 = cz0, ch0 = cz0, ch1 = cz0;
        if (hp) {
#pragma unroll
            for (int kt = 0; kt < 8; ++kt) {
                const int ko = kt * 32 + lq * 8;
                s8v am = (ln < 2) ? frag(&mBL[par][ln][ko]) : zfrag();
                s8v aa = (ln < 2) ? frag(&armBL[par][ln][ko]) : zfrag();
                cz0 = __builtin_amdgcn_mfma_f32_16x16x32_bf16(am, wz0[kt], cz0, 0, 0, 0);
                cz1 = __builtin_amdgcn_mfma_f32_16x16x32_bf16(am, wz1[kt], cz1, 0, 0, 0);
                ch0 = __builtin_amdgcn_mfma_f32_16x16x32_bf16(aa, wh0[kt], ch0, 0, 0, 0);
                ch1 = __builtin_amdgcn_mfma_f32_16x16x32_bf16(aa, wh1[kt], ch1, 0, 0, 0);
            }
        }

        // ---- phase A finalize (in-register, owner lanes) ----
        if (owner) {
            float pz[4] = {cz0[0], cz1[0], cz0[1], cz1[1]};
            float ph[4] = {ch0[0], ch1[0], ch0[1], ch1[1]};
#pragma unroll
            for (int i = 0; i < 4; ++i) {
                const int tree = i >> 1, c = (i & 1) ? c1 : c0;
                float az = cxz[i], ah = cxh[i], sold = 0.f;
                if (hp) { az += pz[i]; ah += ph[i]; sold = mF[i]; }
                float z = sigm(az), mt = tanhf(ah);
                float me = sold + z * (mt - sold);
                float hv = fwd ? me : (me + chsp[i]);
                hsb[(t * NTREE + b0 + tree) * HD + c] = f2bf(hv);
                mF[i] = me;
                mBL[nxt][tree][c] = f2bf(me);
            }
        }
        bar_lgkm();

        // ---- phase B MFMA: ar = m_e @ Ur (B-frags from LDS) ----
        f4v cr0 = (f4v){0.f,0.f,0.f,0.f}, cr1 = cr0;
#pragma unroll
        for (int kt = 0; kt < 8; ++kt) {
            const int ko = kt * 32 + lq * 8;
            s8v a = (ln < 2) ? frag(&mBL[nxt][ln][ko]) : zfrag();
            s8v b0f = frag(&urL[((T0 * 8 + kt) * 64 + lane) * 8]);
            s8v b1f = frag(&urL[((T1 * 8 + kt) * 64 + lane) * 8]);
            cr0 = __builtin_amdgcn_mfma_f32_16x16x32_bf16(a, b0f, cr0, 0, 0, 0);
            cr1 = __builtin_amdgcn_mfma_f32_16x16x32_bf16(a, b1f, cr1, 0, 0, 0);
        }
        if (owner) {
            float pr[4] = {cr0[0], cr1[0], cr0[1], cr1[1]};
#pragma unroll
            for (int i = 0; i < 4; ++i) {
                const int tree = i >> 1, c = (i & 1) ? c1 : c0;
                armBL[nxt][tree][c] = f2bf(sigm(cxr[i] + pr[i]) * mF[i]);
            }
#pragma unroll
            for (int i = 0; i < 4; ++i) {
                cxz[i] = nxz[i]; cxh[i] = nxh[i]; cxr[i] = nxr[i]; chsp[i] = nhsp[i];
            }
        }
        bar_lgkm();
    }
}

// ---------------------------------------------------------------------------
// Q head, MFMA. 768 wgs (48 trow x 16 tree-groups) x 256 thr. 32 rows/wg.
// ---------------------------------------------------------------------------
#define QG 32
__global__ __launch_bounds__(256) void q3(
    const int* __restrict__ wid,
    const unsigned short* __restrict__ tvB,
    const unsigned short* __restrict__ hsb,
    const unsigned short* __restrict__ W1T,
    const unsigned short* __restrict__ WoT,
    const float* __restrict__ Wb,
    const float* __restrict__ Wob,
    float* __restrict__ acc)
{
    __shared__ unsigned short X1L[QG][328];
    __shared__ unsigned short hidL[QG][264];
    __shared__ int tgts[QG];
    __shared__ float wred[4][QG][4];
    const int tid = threadIdx.x;
    const int wave = tid >> 6, lane = tid & 63;
    const int lq = lane >> 4, ln = lane & 15;
    const int trow = blockIdx.x >> 4;
    const int b0 = (blockIdx.x & 15) * QG;

    if (tid < QG) tgts[tid] = wid[(b0 + tid) * NNODE + trow];
    if (trow == 0) {
        int4 z = make_int4(0, 0, 0, 0);
        for (int idx = tid; idx < QG * 32; idx += 256) {
            int m = idx >> 5, c = idx & 31;
            *(int4*)&X1L[m][c * 8] = z;
        }
    } else {
        const unsigned short* hrow = hsb + (size_t)(trow - 1) * NTREE * HD;
        for (int idx = tid; idx < QG * 32; idx += 256) {
            int m = idx >> 5, c = idx & 31;
            *(int4*)&X1L[m][c * 8] = *(const int4*)&hrow[(b0 + m) * HD + c * 8];
        }
    }
    for (int idx = tid; idx < QG * 8; idx += 256) {
        int m = idx >> 3, c = idx & 7;
        *(int4*)&X1L[m][256 + c * 8] = *(const int4*)&tvB[(b0 + m) * LD + c * 8];
    }
    __syncthreads();

    f4v acc1[2][4];
#pragma unroll
    for (int mt = 0; mt < 2; ++mt)
#pragma unroll
        for (int nt = 0; nt < 4; ++nt) acc1[mt][nt] = (f4v){0.f, 0.f, 0.f, 0.f};
#pragma unroll
    for (int kt = 0; kt < 10; ++kt) {
        s8v a0 = frag(&X1L[ln][kt * 32 + lq * 8]);
        s8v a1 = frag(&X1L[16 + ln][kt * 32 + lq * 8]);
#pragma unroll
        for (int nt = 0; nt < 4; ++nt) {
            int n = wave * 64 + nt * 16 + ln;
            s8v b = frag(&W1T[n * 320 + kt * 32 + lq * 8]);
            acc1[0][nt] = __builtin_amdgcn_mfma_f32_16x16x32_bf16(a0, b, acc1[0][nt], 0, 0, 0);
            acc1[1][nt] = __builtin_amdgcn_mfma_f32_16x16x32_bf16(a1, b, acc1[1][nt], 0, 0, 0);
        }
    }
#pragma unroll
    for (int nt = 0; nt < 4; ++nt) {
        int col = wave * 64 + nt * 16 + ln;
        float wb = Wb[col];
#pragma unroll
        for (int mt = 0; mt < 2; ++mt)
#pragma unroll
            for (int r = 0; r < 4; ++r)
                hidL[mt * 16 + lq * 4 + r][col] = f2bf(fmaxf(acc1[mt][nt][r] + wb, 0.f));
    }
    __syncthreads();

    int rt[2][4];
#pragma unroll
    for (int mt = 0; mt < 2; ++mt)
#pragma unroll
        for (int r = 0; r < 4; ++r) rt[mt][r] = tgts[mt * 16 + lq * 4 + r];
    float mx[2][4], ls[2][4], tg[2][4]; int am[2][4];
#pragma unroll
    for (int mt = 0; mt < 2; ++mt)
#pragma unroll
        for (int r = 0; r < 4; ++r) { mx[mt][r] = -1e30f; ls[mt][r] = 0.f; tg[mt][r] = 0.f; am[mt][r] = 1 << 30; }

    for (int nt = wave; nt < 50; nt += 4) {
        int n = nt * 16 + ln;
        const unsigned short* wrow = WoT + n * 256;
        f4v a2[2];
        a2[0] = (f4v){0.f, 0.f, 0.f, 0.f}; a2[1] = (f4v){0.f, 0.f, 0.f, 0.f};
#pragma unroll
        for (int kt = 0; kt < 8; ++kt) {
            s8v a0 = frag(&hidL[ln][kt * 32 + lq * 8]);
            s8v a1 = frag(&hidL[16 + ln][kt * 32 + lq * 8]);
            s8v b = frag(&wrow[kt * 32 + lq * 8]);
            a2[0] = __builtin_amdgcn_mfma_f32_16x16x32_bf16(a0, b, a2[0], 0, 0, 0);
            a2[1] = __builtin_amdgcn_mfma_f32_16x16x32_bf16(a1, b, a2[1], 0, 0, 0);
        }
        float bias = Wob[n];
#pragma unroll
        for (int mt = 0; mt < 2; ++mt)
#pragma unroll
            for (int r = 0; r < 4; ++r) {
                float v = a2[mt][r] + bias;
                if (n == rt[mt][r]) tg[mt][r] = v;
                float nm = fmaxf(mx[mt][r], v);
                ls[mt][r] = ls[mt][r] * __expf(mx[mt][r] - nm) + __expf(v - nm);
                if (v > mx[mt][r]) am[mt][r] = n;
                mx[mt][r] = nm;
            }
    }

#pragma unroll
    for (int s = 1; s < 16; s <<= 1) {
#pragma unroll
        for (int mt = 0; mt < 2; ++mt)
#pragma unroll
            for (int r = 0; r < 4; ++r) {
                float mo = __shfl_xor(mx[mt][r], s);
                float lo = __shfl_xor(ls[mt][r], s);
                int   ao = __shfl_xor(am[mt][r], s);
                float to = __shfl_xor(tg[mt][r], s);
                tg[mt][r] += to;
                float nm = fmaxf(mx[mt][r], mo);
                ls[mt][r] = ls[mt][r] * __expf(mx[mt][r] - nm) + lo * __expf(mo - nm);
                if (mo > mx[mt][r] || (mo == mx[mt][r] && ao < am[mt][r])) am[mt][r] = ao;
                mx[mt][r] = nm;
            }
    }
    if (ln == 0) {
#pragma unroll
        for (int mt = 0; mt < 2; ++mt)
#pragma unroll
            for (int r = 0; r < 4; ++r) {
                int row = mt * 16 + lq * 4 + r;
                wred[wave][row][0] = mx[mt][r];
                wred[wave][row][1] = ls[mt][r];
                wred[wave][row][2] = __int_as_float(am[mt][r]);
                wred[wave][row][3] = tg[mt][r];
            }
    }
    __syncthreads();

    float lossv = 0.f, corrv = 0.f;
    if (tid < QG) {
        float m_ = -1e30f, l_ = 0.f, t_ = 0.f; int a_ = 1 << 30;
#pragma unroll
        for (int w = 0; w < 4; ++w) {
            float mo = wred[w][tid][0], lo = wred[w][tid][1], to = wred[w][tid][3];
            int ao = __float_as_int(wred[w][tid][2]);
            t_ += to;
            float nm = fmaxf(m_, mo);
            l_ = l_ * __expf(m_ - nm) + lo * __expf(mo - nm);
            if (mo > m_ || (mo == m_ && ao < a_)) a_ = ao;
            m_ = nm;
        }
        lossv = m_ + logf(l_) - t_;
        corrv = (a_ == tgts[tid]) ? 1.f : 0.f;
    }
    if (wave == 0) {
        for (int s = 32; s; s >>= 1) {
            lossv += __shfl_down(lossv, s);
            corrv += __shfl_down(corrv, s);
        }
        if (tid == 0) {
            int slot = blockIdx.x & 255;
            atomicAdd(&acc[0 * 256 + slot], lossv);
            atomicAdd(&acc[2 * 256 + slot], corrv);
        }
    }
}

// ---------------------------------------------------------------------------
// P head, MFMA. 1520 wgs (95 trow x 16 groups) x 256 thr. 32 rows/wg.
// ---------------------------------------------------------------------------
#define PG 32
__global__ __launch_bounds__(256) void p3(
    const int* __restrict__ wid,
    const unsigned short* __restrict__ tvB,
    const unsigned short* __restrict__ embB,
    const unsigned short* __restrict__ hsb,
    const unsigned short* __restrict__ UwT,
    const float* __restrict__ Ub,
    const float* __restrict__ Usw, const float* __restrict__ Usb,
    float* __restrict__ acc)
{
    __shared__ unsigned short XL[PG][584];
    __shared__ int widL[PG];
    __shared__ float wredp[4][PG];
    const int tid = threadIdx.x;
    const int wave = tid >> 6, lane = tid & 63;
    const int lq = lane >> 4, ln = lane & 15;
    const int trow = blockIdx.x >> 4;
    const int b0 = (blockIdx.x & 15) * PG;
    const int node = (trow == 0) ? 0 : ((trow <= NFWD) ? trow : (TSTEP - trow));

    if (tid < PG) widL[tid] = wid[(b0 + tid) * NNODE + node];
    __syncthreads();

    for (int idx = tid; idx < PG * 32; idx += 256) {
        int m = idx >> 5, c = idx & 31;
        *(int4*)&XL[m][c * 8] = *(const int4*)&embB[widL[m] * HD + c * 8];
    }
    if (trow == 0) {
        int4 z = make_int4(0, 0, 0, 0);
        for (int idx = tid; idx < PG * 32; idx += 256) {
            int m = idx >> 5, c = idx & 31;
            *(int4*)&XL[m][256 + c * 8] = z;
        }
    } else {
        const unsigned short* hrow = hsb + (size_t)(trow - 1) * NTREE * HD;
        for (int idx = tid; idx < PG * 32; idx += 256) {
            int m = idx >> 5, c = idx & 31;
            *(int4*)&XL[m][256 + c * 8] = *(const int4*)&hrow[(b0 + m) * HD + c * 8];
        }
    }
    for (int idx = tid; idx < PG * 8; idx += 256) {
        int m = idx >> 3, c = idx & 7;
        *(int4*)&XL[m][512 + c * 8] = *(const int4*)&tvB[(b0 + m) * LD + c * 8];
    }
    __syncthreads();

    f4v a1[2][4];
#pragma unroll
    for (int mt = 0; mt < 2; ++mt)
#pragma unroll
        for (int nt = 0; nt < 4; ++nt) a1[mt][nt] = (f4v){0.f, 0.f, 0.f, 0.f};
    for (int kt = 0; kt < 18; ++kt) {
        s8v a0 = frag(&XL[ln][kt * 32 + lq * 8]);
        s8v am_ = frag(&XL[16 + ln][kt * 32 + lq * 8]);
#pragma unroll
        for (int nt = 0; nt < 4; ++nt) {
            int n = wave * 64 + nt * 16 + ln;
            s8v b = frag(&UwT[n * 576 + kt * 32 + lq * 8]);
            a1[0][nt] = __builtin_amdgcn_mfma_f32_16x16x32_bf16(a0, b, a1[0][nt], 0, 0, 0);
            a1[1][nt] = __builtin_amdgcn_mfma_f32_16x16x32_bf16(am_, b, a1[1][nt], 0, 0, 0);
        }
    }
    float part[2][4] = {{0, 0, 0, 0}, {0, 0, 0, 0}};
#pragma unroll
    for (int nt = 0; nt < 4; ++nt) {
        int n = wave * 64 + nt * 16 + ln;
        float ub = Ub[n], us = Usw[n];
#pragma unroll
        for (int mt = 0; mt < 2; ++mt)
#pragma unroll
            for (int r = 0; r < 4; ++r)
                part[mt][r] += fmaxf(a1[mt][nt][r] + ub, 0.f) * us;
    }
#pragma unroll
    for (int s = 1; s < 16; s <<= 1) {
#pragma unroll
        for (int mt = 0; mt < 2; ++mt)
#pragma unroll
            for (int r = 0; r < 4; ++r)
                part[mt][r] += __shfl_xor(part[mt][r], s);
    }
    if (ln == 0) {
#pragma unroll
        for (int mt = 0; mt < 2; ++mt)
#pragma unroll
            for (int r = 0; r < 4; ++r)
                wredp[wave][mt * 16 + lq * 4 + r] = part[mt][r];
    }
    __syncthreads();

    float lossv = 0.f, corrv = 0.f;
    if (tid < PG) {
        float p = wredp[0][tid] + wredp[1][tid] + wredp[2][tid] + wredp[3][tid] + Usb[0];
        float tgt = (trow < NFWD) ? 1.f : 0.f;
        lossv = fmaxf(p, 0.f) - p * tgt + log1pf(expf(-fabsf(p)));
        corrv = (((p > 0.f) ? 1 : 0) == ((trow < NFWD) ? 1 : 0)) ? 1.f : 0.f;
    }
    if (wave == 0) {
        for (int s = 32; s; s >>= 1) {
            lossv += __shfl_down(lossv, s);
            corrv += __shfl_down(corrv, s);
        }
        if (tid == 0) {
            int slot = blockIdx.x & 255;
            atomicAdd(&acc[1 * 256 + slot], lossv);
            atomicAdd(&acc[3 * 256 + slot], corrv);
        }
    }
}

__global__ void init_kernel(float* __restrict__ acc) {
    acc[threadIdx.x] = 0.f;   // 1024 slots
}

__global__ void fin_kernel(const float* __restrict__ acc, float* __restrict__ out) {
    const int tid = threadIdx.x;
    const int c = tid >> 6, lane = tid & 63;
    float v = 0.f;
    for (int i = lane; i < 256; i += 64) v += acc[c * 256 + i];
    for (int s = 32; s; s >>= 1) v += __shfl_down(v, s);
    if (lane == 0) {
        const float sc[4] = {1.f / 512.f, 1.f / 512.f, 1.f / 24576.f, 1.f / 48640.f};
        out[c] = v * sc[c];
    }
}

extern "C" void kernel_launch(void* const* d_in, const int* in_sizes, int n_in,
                              void* d_out, int out_size, void* d_ws, size_t ws_size,
                              hipStream_t stream) {
    const int*   wid  = (const int*)  d_in[12];
    const float* tv   = (const float*)d_in[13];
    const float* emb  = (const float*)d_in[14];
    const float* Wz   = (const float*)d_in[15];
    const float* bz   = (const float*)d_in[16];
    const float* Wr   = (const float*)d_in[17];
    const float* Ur   = (const float*)d_in[18];
    const float* br   = (const float*)d_in[19];
    const float* Wh   = (const float*)d_in[20];
    const float* bh   = (const float*)d_in[21];
    const float* Ww   = (const float*)d_in[22];
    const float* Wb   = (const float*)d_in[23];
    const float* Uw   = (const float*)d_in[24];
    const float* Ubias= (const float*)d_in[25];
    const float* Wow  = (const float*)d_in[26];
    const float* Wob  = (const float*)d_in[27];
    const float* Usw  = (const float*)d_in[28];
    const float* Usb  = (const float*)d_in[29];

    char* w = (char*)d_ws;
    float* accb = (float*)w;                                 // 4 KB
    float* xzT  = (float*)(w + 4096);                        // 800*256 f32
    float* xhT  = (float*)(w + 823296);
    float* xrT  = (float*)(w + 1642496);
    unsigned short* WzT2 = (unsigned short*)(w + 2461696);   // [256 n][256 k] bf16
    unsigned short* WhT2 = (unsigned short*)(w + 2592768);
    unsigned short* UrT2 = (unsigned short*)(w + 2723840);
    unsigned short* hsb  = (unsigned short*)(w + 2854912);   // 94*512*256 bf16
    unsigned short* W1T  = (unsigned short*)(w + 27496448);  // [256][320]
    unsigned short* WoT  = (unsigned short*)(w + 27660288);  // [800][256]
    unsigned short* UwT  = (unsigned short*)(w + 28069888);  // [256][576]
    unsigned short* embB = (unsigned short*)(w + 28364800);  // [800][256]
    unsigned short* tvB  = (unsigned short*)(w + 28774400);  // [512][64]

    init_kernel<<<1, 1024, 0, stream>>>(accb);
    prep_xproj<<<VOC / PV, 256, 0, stream>>>(emb, Wz, bz, Wh, bh, Wr, br, xzT, xhT, xrT);
    tcvt3<<<768, 256, 0, stream>>>(Wz, Wh, Ur, WzT2, WhT2, UrT2);
    tcvtQ<<<1312, 256, 0, stream>>>(Ww, Wow, Uw, W1T, WoT, UwT);
    cvtE<<<(VOC * HD + NTREE * LD + 255) / 256, 256, 0, stream>>>(emb, tv, embB, tvB);
    gru7<<<NTREE / 2, 512, 0, stream>>>(wid, xzT, xhT, xrT, WzT2, WhT2, UrT2, hsb);
    q3<<<48 * 16, 256, 0, stream>>>(wid, tvB, hsb, W1T, WoT, Wb, Wob, accb);
    p3<<<95 * 16, 256, 0, stream>>>(wid, tvB, embB, hsb, UwT, Ubias, Usw, Usb, accb);
    fin_kernel<<<1, 256, 0, stream>>>(accb, (float*)d_out);
}

// Round 9
// 489.581 us; speedup vs baseline: 2.4398x; 1.1588x over previous
//
#include <hip/hip_runtime.h>
#include <math.h>

#define NTREE 512
#define NNODE 48
#define HD 256
#define LD 64
#define VOC 800
#define TSTEP 94
#define NFWD 47

typedef __attribute__((ext_vector_type(8))) short s8v;   // 8 bf16 (4 VGPRs)
typedef __attribute__((ext_vector_type(4))) float f4v;   // 4 fp32 acc

__device__ __forceinline__ float sigm(float x) { return 1.f / (1.f + expf(-x)); }
// fast device transcendentals (v_exp_f32 + v_rcp_f32), GRU-only
__device__ __forceinline__ float sigm_f(float x) {
    return __builtin_amdgcn_rcpf(1.f + __expf(-x));
}
__device__ __forceinline__ float tanh_f(float x) {
    return 1.f - 2.f * __builtin_amdgcn_rcpf(1.f + __expf(2.f * x));
}

__device__ __forceinline__ float bfu(unsigned short u) {
    union { unsigned int i; float f; } c; c.i = ((unsigned int)u) << 16; return c.f;
}
__device__ __forceinline__ unsigned short f2bf(float f) {
    union { float f; unsigned int u; } c; c.f = f;
    return (unsigned short)((c.u + 0x7fffu + ((c.u >> 16) & 1u)) >> 16);
}
__device__ __forceinline__ s8v frag(const unsigned short* p) {
    union { int4 i; s8v v; } u; u.i = *(const int4*)p; return u.v;
}
__device__ __forceinline__ s8v zfrag() {
    union { int4 i; s8v v; } u; u.i = make_int4(0, 0, 0, 0); return u.v;
}
// LDS-only barrier: global ops (hsb stores, gathers) stay in flight.
__device__ __forceinline__ void bar_lgkm() {
    asm volatile("s_waitcnt lgkmcnt(0)\n\ts_barrier" ::: "memory");
}

// ---------------------------------------------------------------------------
// Precompute x-projections for all 800 vocab words (biases folded in).
// ---------------------------------------------------------------------------
#define PV 8
__global__ __launch_bounds__(256) void prep_xproj(
    const float* __restrict__ emb,
    const float* __restrict__ Wz, const float* __restrict__ bz,
    const float* __restrict__ Wh, const float* __restrict__ bh,
    const float* __restrict__ Wr, const float* __restrict__ br,
    float* __restrict__ xzT, float* __restrict__ xhT, float* __restrict__ xrT)
{
    __shared__ float embL[PV][HD];
    const int j = threadIdx.x;
    const int v0 = blockIdx.x * PV;
    for (int r = 0; r < PV; ++r) embL[r][j] = emb[(v0 + r) * HD + j];
    __syncthreads();

    float az[PV], ah[PV], ar[PV];
#pragma unroll
    for (int r = 0; r < PV; ++r) { az[r] = bz[j]; ah[r] = bh[j]; ar[r] = br[j]; }
    for (int i = 0; i < HD; i += 4) {
        float wz0 = Wz[(i + 0) * HD + j], wz1 = Wz[(i + 1) * HD + j];
        float wz2 = Wz[(i + 2) * HD + j], wz3 = Wz[(i + 3) * HD + j];
        float wh0 = Wh[(i + 0) * HD + j], wh1 = Wh[(i + 1) * HD + j];
        float wh2 = Wh[(i + 2) * HD + j], wh3 = Wh[(i + 3) * HD + j];
        float wr0 = Wr[(i + 0) * HD + j], wr1 = Wr[(i + 1) * HD + j];
        float wr2 = Wr[(i + 2) * HD + j], wr3 = Wr[(i + 3) * HD + j];
#pragma unroll
        for (int r = 0; r < PV; ++r) {
            float4 e = *(const float4*)&embL[r][i];
            az[r] += e.x * wz0 + e.y * wz1 + e.z * wz2 + e.w * wz3;
            ah[r] += e.x * wh0 + e.y * wh1 + e.z * wh2 + e.w * wh3;
            ar[r] += e.x * wr0 + e.y * wr1 + e.z * wr2 + e.w * wr3;
        }
    }
#pragma unroll
    for (int r = 0; r < PV; ++r) {
        xzT[(v0 + r) * HD + j] = az[r];
        xhT[(v0 + r) * HD + j] = ah[r];
        xrT[(v0 + r) * HD + j] = ar[r];
    }
}

// Fused transpose-convert for the three 256x256 GRU matrices.
__global__ __launch_bounds__(256) void tcvt3(
    const float* __restrict__ Wz, const float* __restrict__ Wh,
    const float* __restrict__ Ur,
    unsigned short* __restrict__ WzT, unsigned short* __restrict__ WhT,
    unsigned short* __restrict__ UrT)
{
    const int which = blockIdx.x >> 8, n = blockIdx.x & 255, k = threadIdx.x;
    const float* src = (which == 0) ? (Wz + HD * HD) : (which == 1) ? (Wh + HD * HD) : Ur;
    unsigned short* dst = (which == 0) ? WzT : (which == 1) ? WhT : UrT;
    dst[n * HD + k] = f2bf(src[k * HD + n]);
}

// Fused transpose-convert for head matrices: W1T[256][320], WoT[800][256], UwT[256][576].
__global__ __launch_bounds__(256) void tcvtQ(
    const float* __restrict__ Ww, const float* __restrict__ Wow,
    const float* __restrict__ Uw,
    unsigned short* __restrict__ W1T, unsigned short* __restrict__ WoT,
    unsigned short* __restrict__ UwT)
{
    int b = blockIdx.x;
    if (b < 256) {
        for (int k = threadIdx.x; k < 320; k += 256)
            W1T[b * 320 + k] = f2bf(Ww[k * 256 + b]);
    } else if (b < 1056) {
        int n = b - 256;
        WoT[n * 256 + threadIdx.x] = f2bf(Wow[threadIdx.x * VOC + n]);
    } else {
        int n = b - 1056;
        for (int k = threadIdx.x; k < 576; k += 256)
            UwT[n * 576 + k] = f2bf(Uw[k * 256 + n]);
    }
}

// Fused bf16 casts: embB (800*256) then tvB (512*64).
__global__ __launch_bounds__(256) void cvtE(
    const float* __restrict__ emb, const float* __restrict__ tv,
    unsigned short* __restrict__ embB, unsigned short* __restrict__ tvB)
{
    int idx = blockIdx.x * 256 + threadIdx.x;
    if (idx < VOC * HD) embB[idx] = f2bf(emb[idx]);
    else {
        int i2 = idx - VOC * HD;
        if (i2 < NTREE * LD) tvB[i2] = f2bf(tv[i2]);
    }
}

// ---------------------------------------------------------------------------
// GRU v8 = gru4 shape + lgkm-only barriers + register-resident gathers + fast
// transcendentals. 256 wgs x 512 thr (8 waves, 2/SIMD), 2 trees/wg.
// Wave w owns col-tiles 2w,2w+1 of Wz/Wh IN REGISTERS (32 frags = 128 regs);
// Ur in LDS fragment-contiguous (128 KB). Finalize spread over all 512
// threads via the (trF,chF)=tid mapping (1 element each); az/ah/ar cross from
// MFMA C-frags to finalize threads through small LDS arrays. x-projections
// prefetched one step ahead per-thread (coalesced, registers only).
// 4 LDS-only barriers/step -- no vmcnt drain anywhere in the loop.
// ---------------------------------------------------------------------------
__global__ __launch_bounds__(512, 2) void gru8(
    const int* __restrict__ wid,
    const float* __restrict__ xzT, const float* __restrict__ xhT,
    const float* __restrict__ xrT,
    const unsigned short* __restrict__ WzT, const unsigned short* __restrict__ WhT,
    const unsigned short* __restrict__ UrT,
    unsigned short* __restrict__ hsb)
{
    __shared__ unsigned short urL[16 * 8 * 64 * 8];   // 128 KB [tile][kt][lane][8]
    __shared__ unsigned short mBL[2][2][HD], armBL[2][2][HD];
    __shared__ float azL[2][HD], ahL[2][HD], arL[2][HD];
    __shared__ int widL[2][NNODE];

    const int tid = threadIdx.x;
    const int wave = tid >> 6, lane = tid & 63;
    const int lq = lane >> 4, ln = lane & 15;
    const int trF = tid >> 8, chF = tid & 255;
    const int b0 = blockIdx.x * 2;
    const int T0 = 2 * wave, T1 = T0 + 1;
    const bool owner = (lq == 0);

    if (tid < 2 * NNODE) widL[tid / NNODE][tid % NNODE] =
        wid[(b0 + tid / NNODE) * NNODE + (tid % NNODE)];

    // one-time: Ur -> LDS fragment-contiguous
#pragma unroll
    for (int s = 0; s < 16; ++s) {
        *(int4*)&urL[((s * 8 + wave) * 64 + lane) * 8] =
            *(const int4*)&UrT[(s * 16 + ln) * HD + wave * 32 + lq * 8];
    }

    // loop-invariant phase-A weight fragments: 32 frags = 128 regs
    s8v wz0[8], wz1[8], wh0[8], wh1[8];
#pragma unroll
    for (int kt = 0; kt < 8; ++kt) {
        const int ko = kt * 32 + lq * 8;
        wz0[kt] = frag(&WzT[(T0 * 16 + ln) * HD + ko]);
        wz1[kt] = frag(&WzT[(T1 * 16 + ln) * HD + ko]);
        wh0[kt] = frag(&WhT[(T0 * 16 + ln) * HD + ko]);
        wh1[kt] = frag(&WhT[(T1 * 16 + ln) * HD + ko]);
    }
    __syncthreads();   // widL + urL visible

    // per-thread gather state for the (trF,chF) element, double-buffered
    float cxz, cxh, cxr, chsp = 0.f, me = 0.f;
    float nxz = 0.f, nxh = 0.f, nxr = 0.f, nhsp = 0.f;
    {   // prologue: t=0 (src=0, dst=1)
        const int ws = widL[trF][0], wd = widL[trF][1];
        cxz = xzT[ws * HD + chF];
        cxh = xhT[ws * HD + chF];
        cxr = xrT[wd * HD + chF];
    }

#pragma unroll 2
    for (int t = 0; t < TSTEP; ++t) {
        const int par = t & 1, nxt = par ^ 1;
        const bool fwd = t < NFWD;
        const bool hp = (t != 0) && (t != NFWD);

        // ---- prefetch for t+1 (registers only; overlaps MFMA + barriers) ----
        {
            if (t == NFWD)   // this step's hsp (row 45), written ~2 steps ago
                chsp = bfu(hsb[((NFWD - 2) * NTREE + b0 + trF) * HD + chF]);
            const int tn = t + 1;
            if (tn < TSTEP) {
                const bool fwdn = tn < NFWD;
                const int un = TSTEP - tn;
                const int srcn = fwdn ? tn : un;
                const int dstn = fwdn ? (tn + 1) : (un - 1);
                const int ws = widL[trF][srcn], wd = widL[trF][dstn];
                nxz = xzT[ws * HD + chF];
                nxh = xhT[ws * HD + chF];
                nxr = xrT[wd * HD + chF];
                nhsp = 0.f;
                if (tn > NFWD && dstn > 0)   // row dstn-1 written >=3 steps ago
                    nhsp = bfu(hsb[((dstn - 1) * NTREE + b0 + trF) * HD + chF]);
            }
        }

        // ---- phase A MFMA: az (Wz x m), ah (Wh x arm) for own 2 tiles ----
        if (hp) {
            f4v cz0 = (f4v){0.f,0.f,0.f,0.f}, cz1 = cz0, ch0 = cz0, ch1 = cz0;
#pragma unroll
            for (int kt = 0; kt < 8; ++kt) {
                const int ko = kt * 32 + lq * 8;
                s8v am = (ln < 2) ? frag(&mBL[par][ln][ko]) : zfrag();
                s8v aa = (ln < 2) ? frag(&armBL[par][ln][ko]) : zfrag();
                cz0 = __builtin_amdgcn_mfma_f32_16x16x32_bf16(am, wz0[kt], cz0, 0, 0, 0);
                cz1 = __builtin_amdgcn_mfma_f32_16x16x32_bf16(am, wz1[kt], cz1, 0, 0, 0);
                ch0 = __builtin_amdgcn_mfma_f32_16x16x32_bf16(aa, wh0[kt], ch0, 0, 0, 0);
                ch1 = __builtin_amdgcn_mfma_f32_16x16x32_bf16(aa, wh1[kt], ch1, 0, 0, 0);
            }
            if (owner) {   // C rows 0,1 -> LDS for the finalize threads
                azL[0][T0 * 16 + ln] = cz0[0]; azL[1][T0 * 16 + ln] = cz0[1];
                azL[0][T1 * 16 + ln] = cz1[0]; azL[1][T1 * 16 + ln] = cz1[1];
                ahL[0][T0 * 16 + ln] = ch0[0]; ahL[1][T0 * 16 + ln] = ch0[1];
                ahL[0][T1 * 16 + ln] = ch1[0]; ahL[1][T1 * 16 + ln] = ch1[1];
            }
        }
        bar_lgkm();

        // ---- finalize A (all 512 threads, 1 element each) ----
        {
            float az = cxz, ah = cxh, sold = 0.f;
            if (hp) { az += azL[trF][chF]; ah += ahL[trF][chF]; sold = me; }
            float z = sigm_f(az), mt = tanh_f(ah);
            me = sold + z * (mt - sold);
            float hv = fwd ? me : (me + chsp);
            hsb[(t * NTREE + b0 + trF) * HD + chF] = f2bf(hv);
            mBL[nxt][trF][chF] = f2bf(me);
        }
        bar_lgkm();

        // ---- phase B MFMA: ar = m_e @ Ur (B from LDS) ----
        {
            f4v cr0 = (f4v){0.f,0.f,0.f,0.f}, cr1 = cr0;
#pragma unroll
            for (int kt = 0; kt < 8; ++kt) {
                const int ko = kt * 32 + lq * 8;
                s8v a = (ln < 2) ? frag(&mBL[nxt][ln][ko]) : zfrag();
                s8v b0f = frag(&urL[((T0 * 8 + kt) * 64 + lane) * 8]);
                s8v b1f = frag(&urL[((T1 * 8 + kt) * 64 + lane) * 8]);
                cr0 = __builtin_amdgcn_mfma_f32_16x16x32_bf16(a, b0f, cr0, 0, 0, 0);
                cr1 = __builtin_amdgcn_mfma_f32_16x16x32_bf16(a, b1f, cr1, 0, 0, 0);
            }
            if (owner) {
                arL[0][T0 * 16 + ln] = cr0[0]; arL[1][T0 * 16 + ln] = cr0[1];
                arL[0][T1 * 16 + ln] = cr1[0]; arL[1][T1 * 16 + ln] = cr1[1];
            }
        }
        bar_lgkm();

        // ---- finalize B (all 512 threads) ----
        {
            float r = sigm_f(cxr + arL[trF][chF]);
            armBL[nxt][trF][chF] = f2bf(r * me);
            cxz = nxz; cxh = nxh; cxr = nxr; chsp = nhsp;
        }
        bar_lgkm();
    }
}

// ---------------------------------------------------------------------------
// Q head, MFMA. 768 wgs (48 trow x 16 tree-groups) x 256 thr. 32 rows/wg.
// ---------------------------------------------------------------------------
#define QG 32
__global__ __launch_bounds__(256) void q3(
    const int* __restrict__ wid,
    const unsigned short* __restrict__ tvB,
    const unsigned short* __restrict__ hsb,
    const unsigned short* __restrict__ W1T,
    const unsigned short* __restrict__ WoT,
    const float* __restrict__ Wb,
    const float* __restrict__ Wob,
    float* __restrict__ acc)
{
    __shared__ unsigned short X1L[QG][328];
    __shared__ unsigned short hidL[QG][264];
    __shared__ int tgts[QG];
    __shared__ float wred[4][QG][4];
    const int tid = threadIdx.x;
    const int wave = tid >> 6, lane = tid & 63;
    const int lq = lane >> 4, ln = lane & 15;
    const int trow = blockIdx.x >> 4;
    const int b0 = (blockIdx.x & 15) * QG;

    if (tid < QG) tgts[tid] = wid[(b0 + tid) * NNODE + trow];
    if (trow == 0) {
        int4 z = make_int4(0, 0, 0, 0);
        for (int idx = tid; idx < QG * 32; idx += 256) {
            int m = idx >> 5, c = idx & 31;
            *(int4*)&X1L[m][c * 8] = z;
        }
    } else {
        const unsigned short* hrow = hsb + (size_t)(trow - 1) * NTREE * HD;
        for (int idx = tid; idx < QG * 32; idx += 256) {
            int m = idx >> 5, c = idx & 31;
            *(int4*)&X1L[m][c * 8] = *(const int4*)&hrow[(b0 + m) * HD + c * 8];
        }
    }
    for (int idx = tid; idx < QG * 8; idx += 256) {
        int m = idx >> 3, c = idx & 7;
        *(int4*)&X1L[m][256 + c * 8] = *(const int4*)&tvB[(b0 + m) * LD + c * 8];
    }
    __syncthreads();

    f4v acc1[2][4];
#pragma unroll
    for (int mt = 0; mt < 2; ++mt)
#pragma unroll
        for (int nt = 0; nt < 4; ++nt) acc1[mt][nt] = (f4v){0.f, 0.f, 0.f, 0.f};
#pragma unroll
    for (int kt = 0; kt < 10; ++kt) {
        s8v a0 = frag(&X1L[ln][kt * 32 + lq * 8]);
        s8v a1 = frag(&X1L[16 + ln][kt * 32 + lq * 8]);
#pragma unroll
        for (int nt = 0; nt < 4; ++nt) {
            int n = wave * 64 + nt * 16 + ln;
            s8v b = frag(&W1T[n * 320 + kt * 32 + lq * 8]);
            acc1[0][nt] = __builtin_amdgcn_mfma_f32_16x16x32_bf16(a0, b, acc1[0][nt], 0, 0, 0);
            acc1[1][nt] = __builtin_amdgcn_mfma_f32_16x16x32_bf16(a1, b, acc1[1][nt], 0, 0, 0);
        }
    }
#pragma unroll
    for (int nt = 0; nt < 4; ++nt) {
        int col = wave * 64 + nt * 16 + ln;
        float wb = Wb[col];
#pragma unroll
        for (int mt = 0; mt < 2; ++mt)
#pragma unroll
            for (int r = 0; r < 4; ++r)
                hidL[mt * 16 + lq * 4 + r][col] = f2bf(fmaxf(acc1[mt][nt][r] + wb, 0.f));
    }
    __syncthreads();

    int rt[2][4];
#pragma unroll
    for (int mt = 0; mt < 2; ++mt)
#pragma unroll
        for (int r = 0; r < 4; ++r) rt[mt][r] = tgts[mt * 16 + lq * 4 + r];
    float mx[2][4], ls[2][4], tg[2][4]; int am[2][4];
#pragma unroll
    for (int mt = 0; mt < 2; ++mt)
#pragma unroll
        for (int r = 0; r < 4; ++r) { mx[mt][r] = -1e30f; ls[mt][r] = 0.f; tg[mt][r] = 0.f; am[mt][r] = 1 << 30; }

    for (int nt = wave; nt < 50; nt += 4) {
        int n = nt * 16 + ln;
        const unsigned short* wrow = WoT + n * 256;
        f4v a2[2];
        a2[0] = (f4v){0.f, 0.f, 0.f, 0.f}; a2[1] = (f4v){0.f, 0.f, 0.f, 0.f};
#pragma unroll
        for (int kt = 0; kt < 8; ++kt) {
            s8v a0 = frag(&hidL[ln][kt * 32 + lq * 8]);
            s8v a1 = frag(&hidL[16 + ln][kt * 32 + lq * 8]);
            s8v b = frag(&wrow[kt * 32 + lq * 8]);
            a2[0] = __builtin_amdgcn_mfma_f32_16x16x32_bf16(a0, b, a2[0], 0, 0, 0);
            a2[1] = __builtin_amdgcn_mfma_f32_16x16x32_bf16(a1, b, a2[1], 0, 0, 0);
        }
        float bias = Wob[n];
#pragma unroll
        for (int mt = 0; mt < 2; ++mt)
#pragma unroll
            for (int r = 0; r < 4; ++r) {
                float v = a2[mt][r] + bias;
                if (n == rt[mt][r]) tg[mt][r] = v;
                float nm = fmaxf(mx[mt][r], v);
                ls[mt][r] = ls[mt][r] * __expf(mx[mt][r] - nm) + __expf(v - nm);
                if (v > mx[mt][r]) am[mt][r] = n;
                mx[mt][r] = nm;
            }
    }

#pragma unroll
    for (int s = 1; s < 16; s <<= 1) {
#pragma unroll
        for (int mt = 0; mt < 2; ++mt)
#pragma unroll
            for (int r = 0; r < 4; ++r) {
                float mo = __shfl_xor(mx[mt][r], s);
                float lo = __shfl_xor(ls[mt][r], s);
                int   ao = __shfl_xor(am[mt][r], s);
                float to = __shfl_xor(tg[mt][r], s);
                tg[mt][r] += to;
                float nm = fmaxf(mx[mt][r], mo);
                ls[mt][r] = ls[mt][r] * __expf(mx[mt][r] - nm) + lo * __expf(mo - nm);
                if (mo > mx[mt][r] || (mo == mx[mt][r] && ao < am[mt][r])) am[mt][r] = ao;
                mx[mt][r] = nm;
            }
    }
    if (ln == 0) {
#pragma unroll
        for (int mt = 0; mt < 2; ++mt)
#pragma unroll
            for (int r = 0; r < 4; ++r) {
                int row = mt * 16 + lq * 4 + r;
                wred[wave][row][0] = mx[mt][r];
                wred[wave][row][1] = ls[mt][r];
                wred[wave][row][2] = __int_as_float(am[mt][r]);
                wred[wave][row][3] = tg[mt][r];
            }
    }
    __syncthreads();

    float lossv = 0.f, corrv = 0.f;
    if (tid < QG) {
        float m_ = -1e30f, l_ = 0.f, t_ = 0.f; int a_ = 1 << 30;
#pragma unroll
        for (int w = 0; w < 4; ++w) {
            float mo = wred[w][tid][0], lo = wred[w][tid][1], to = wred[w][tid][3];
            int ao = __float_as_int(wred[w][tid][2]);
            t_ += to;
            float nm = fmaxf(m_, mo);
            l_ = l_ * __expf(m_ - nm) + lo * __expf(mo - nm);
            if (mo > m_ || (mo == m_ && ao < a_)) a_ = ao;
            m_ = nm;
        }
        lossv = m_ + logf(l_) - t_;
        corrv = (a_ == tgts[tid]) ? 1.f : 0.f;
    }
    if (wave == 0) {
        for (int s = 32; s; s >>= 1) {
            lossv += __shfl_down(lossv, s);
            corrv += __shfl_down(corrv, s);
        }
        if (tid == 0) {
            int slot = blockIdx.x & 255;
            atomicAdd(&acc[0 * 256 + slot], lossv);
            atomicAdd(&acc[2 * 256 + slot], corrv);
        }
    }
}

// ---------------------------------------------------------------------------
// P head, MFMA. 1520 wgs (95 trow x 16 groups) x 256 thr. 32 rows/wg.
// ---------------------------------------------------------------------------
#define PG 32
__global__ __launch_bounds__(256) void p3(
    const int* __restrict__ wid,
    const unsigned short* __restrict__ tvB,
    const unsigned short* __restrict__ embB,
    const unsigned short* __restrict__ hsb,
    const unsigned short* __restrict__ UwT,
    const float* __restrict__ Ub,
    const float* __restrict__ Usw, const float* __restrict__ Usb,
    float* __restrict__ acc)
{
    __shared__ unsigned short XL[PG][584];
    __shared__ int widL[PG];
    __shared__ float wredp[4][PG];
    const int tid = threadIdx.x;
    const int wave = tid >> 6, lane = tid & 63;
    const int lq = lane >> 4, ln = lane & 15;
    const int trow = blockIdx.x >> 4;
    const int b0 = (blockIdx.x & 15) * PG;
    const int node = (trow == 0) ? 0 : ((trow <= NFWD) ? trow : (TSTEP - trow));

    if (tid < PG) widL[tid] = wid[(b0 + tid) * NNODE + node];
    __syncthreads();

    for (int idx = tid; idx < PG * 32; idx += 256) {
        int m = idx >> 5, c = idx & 31;
        *(int4*)&XL[m][c * 8] = *(const int4*)&embB[widL[m] * HD + c * 8];
    }
    if (trow == 0) {
        int4 z = make_int4(0, 0, 0, 0);
        for (int idx = tid; idx < PG * 32; idx += 256) {
            int m = idx >> 5, c = idx & 31;
            *(int4*)&XL[m][256 + c * 8] = z;
        }
    } else {
        const unsigned short* hrow = hsb + (size_t)(trow - 1) * NTREE * HD;
        for (int idx = tid; idx < PG * 32; idx += 256) {
            int m = idx >> 5, c = idx & 31;
            *(int4*)&XL[m][256 + c * 8] = *(const int4*)&hrow[(b0 + m) * HD + c * 8];
        }
    }
    for (int idx = tid; idx < PG * 8; idx += 256) {
        int m = idx >> 3, c = idx & 7;
        *(int4*)&XL[m][512 + c * 8] = *(const int4*)&tvB[(b0 + m) * LD + c * 8];
    }
    __syncthreads();

    f4v a1[2][4];
#pragma unroll
    for (int mt = 0; mt < 2; ++mt)
#pragma unroll
        for (int nt = 0; nt < 4; ++nt) a1[mt][nt] = (f4v){0.f, 0.f, 0.f, 0.f};
    for (int kt = 0; kt < 18; ++kt) {
        s8v a0 = frag(&XL[ln][kt * 32 + lq * 8]);
        s8v am_ = frag(&XL[16 + ln][kt * 32 + lq * 8]);
#pragma unroll
        for (int nt = 0; nt < 4; ++nt) {
            int n = wave * 64 + nt * 16 + ln;
            s8v b = frag(&UwT[n * 576 + kt * 32 + lq * 8]);
            a1[0][nt] = __builtin_amdgcn_mfma_f32_16x16x32_bf16(a0, b, a1[0][nt], 0, 0, 0);
            a1[1][nt] = __builtin_amdgcn_mfma_f32_16x16x32_bf16(am_, b, a1[1][nt], 0, 0, 0);
        }
    }
    float part[2][4] = {{0, 0, 0, 0}, {0, 0, 0, 0}};
#pragma unroll
    for (int nt = 0; nt < 4; ++nt) {
        int n = wave * 64 + nt * 16 + ln;
        float ub = Ub[n], us = Usw[n];
#pragma unroll
        for (int mt = 0; mt < 2; ++mt)
#pragma unroll
            for (int r = 0; r < 4; ++r)
                part[mt][r] += fmaxf(a1[mt][nt][r] + ub, 0.f) * us;
    }
#pragma unroll
    for (int s = 1; s < 16; s <<= 1) {
#pragma unroll
        for (int mt = 0; mt < 2; ++mt)
#pragma unroll
            for (int r = 0; r < 4; ++r)
                part[mt][r] += __shfl_xor(part[mt][r], s);
    }
    if (ln == 0) {
#pragma unroll
        for (int mt = 0; mt < 2; ++mt)
#pragma unroll
            for (int r = 0; r < 4; ++r)
                wredp[wave][mt * 16 + lq * 4 + r] = part[mt][r];
    }
    __syncthreads();

    float lossv = 0.f, corrv = 0.f;
    if (tid < PG) {
        float p = wredp[0][tid] + wredp[1][tid] + wredp[2][tid] + wredp[3][tid] + Usb[0];
        float tgt = (trow < NFWD) ? 1.f : 0.f;
        lossv = fmaxf(p, 0.f) - p * tgt + log1pf(expf(-fabsf(p)));
        corrv = (((p > 0.f) ? 1 : 0) == ((trow < NFWD) ? 1 : 0)) ? 1.f : 0.f;
    }
    if (wave == 0) {
        for (int s = 32; s; s >>= 1) {
            lossv += __shfl_down(lossv, s);
            corrv += __shfl_down(corrv, s);
        }
        if (tid == 0) {
            int slot = blockIdx.x & 255;
            atomicAdd(&acc[1 * 256 + slot], lossv);
            atomicAdd(&acc[3 * 256 + slot], corrv);
        }
    }
}

__global__ void init_kernel(float* __restrict__ acc) {
    acc[threadIdx.x] = 0.f;   // 1024 slots
}

__global__ void fin_kernel(const float* __restrict__ acc, float* __restrict__ out) {
    const int tid = threadIdx.x;
    const int c = tid >> 6, lane = tid & 63;
    float v = 0.f;
    for (int i = lane; i < 256; i += 64) v += acc[c * 256 + i];
    for (int s = 32; s; s >>= 1) v += __shfl_down(v, s);
    if (lane == 0) {
        const float sc[4] = {1.f / 512.f, 1.f / 512.f, 1.f / 24576.f, 1.f / 48640.f};
        out[c] = v * sc[c];
    }
}

extern "C" void kernel_launch(void* const* d_in, const int* in_sizes, int n_in,
                              void* d_out, int out_size, void* d_ws, size_t ws_size,
                              hipStream_t stream) {
    const int*   wid  = (const int*)  d_in[12];
    const float* tv   = (const float*)d_in[13];
    const float* emb  = (const float*)d_in[14];
    const float* Wz   = (const float*)d_in[15];
    const float* bz   = (const float*)d_in[16];
    const float* Wr   = (const float*)d_in[17];
    const float* Ur   = (const float*)d_in[18];
    const float* br   = (const float*)d_in[19];
    const float* Wh   = (const float*)d_in[20];
    const float* bh   = (const float*)d_in[21];
    const float* Ww   = (const float*)d_in[22];
    const float* Wb   = (const float*)d_in[23];
    const float* Uw   = (const float*)d_in[24];
    const float* Ubias= (const float*)d_in[25];
    const float* Wow  = (const float*)d_in[26];
    const float* Wob  = (const float*)d_in[27];
    const float* Usw  = (const float*)d_in[28];
    const float* Usb  = (const float*)d_in[29];

    char* w = (char*)d_ws;
    float* accb = (float*)w;                                 // 4 KB
    float* xzT  = (float*)(w + 4096);                        // 800*256 f32
    float* xhT  = (float*)(w + 823296);
    float* xrT  = (float*)(w + 1642496);
    unsigned short* WzT2 = (unsigned short*)(w + 2461696);   // [256 n][256 k] bf16
    unsigned short* WhT2 = (unsigned short*)(w + 2592768);
    unsigned short* UrT2 = (unsigned short*)(w + 2723840);
    unsigned short* hsb  = (unsigned short*)(w + 2854912);   // 94*512*256 bf16
    unsigned short* W1T  = (unsigned short*)(w + 27496448);  // [256][320]
    unsigned short* WoT  = (unsigned short*)(w + 27660288);  // [800][256]
    unsigned short* UwT  = (unsigned short*)(w + 28069888);  // [256][576]
    unsigned short* embB = (unsigned short*)(w + 28364800);  // [800][256]
    unsigned short* tvB  = (unsigned short*)(w + 28774400);  // [512][64]

    init_kernel<<<1, 1024, 0, stream>>>(accb);
    prep_xproj<<<VOC / PV, 256, 0, stream>>>(emb, Wz, bz, Wh, bh, Wr, br, xzT, xhT, xrT);
    tcvt3<<<768, 256, 0, stream>>>(Wz, Wh, Ur, WzT2, WhT2, UrT2);
    tcvtQ<<<1312, 256, 0, stream>>>(Ww, Wow, Uw, W1T, WoT, UwT);
    cvtE<<<(VOC * HD + NTREE * LD + 255) / 256, 256, 0, stream>>>(emb, tv, embB, tvB);
    gru8<<<NTREE / 2, 512, 0, stream>>>(wid, xzT, xhT, xrT, WzT2, WhT2, UrT2, hsb);
    q3<<<48 * 16, 256, 0, stream>>>(wid, tvB, hsb, W1T, WoT, Wb, Wob, accb);
    p3<<<95 * 16, 256, 0, stream>>>(wid, tvB, embB, hsb, UwT, Ubias, Usw, Usb, accb);
    fin_kernel<<<1, 256, 0, stream>>>(accb, (float*)d_out);
}

// Round 10
// 472.732 us; speedup vs baseline: 2.5267x; 1.0356x over previous
//
#include <hip/hip_runtime.h>
#include <math.h>

#define NTREE 512
#define NNODE 48
#define HD 256
#define LD 64
#define VOC 800
#define TSTEP 94
#define NFWD 47

typedef __attribute__((ext_vector_type(8))) short s8v;   // 8 bf16 (4 VGPRs)
typedef __attribute__((ext_vector_type(4))) float f4v;   // 4 fp32 acc

__device__ __forceinline__ float sigm(float x) { return 1.f / (1.f + expf(-x)); }
// fast device transcendentals (v_exp_f32 + v_rcp_f32), GRU-only
__device__ __forceinline__ float sigm_f(float x) {
    return __builtin_amdgcn_rcpf(1.f + __expf(-x));
}
__device__ __forceinline__ float tanh_f(float x) {
    return 1.f - 2.f * __builtin_amdgcn_rcpf(1.f + __expf(2.f * x));
}

__device__ __forceinline__ float bfu(unsigned short u) {
    union { unsigned int i; float f; } c; c.i = ((unsigned int)u) << 16; return c.f;
}
__device__ __forceinline__ unsigned short f2bf(float f) {
    union { float f; unsigned int u; } c; c.f = f;
    return (unsigned short)((c.u + 0x7fffu + ((c.u >> 16) & 1u)) >> 16);
}
__device__ __forceinline__ s8v frag(const unsigned short* p) {
    union { int4 i; s8v v; } u; u.i = *(const int4*)p; return u.v;
}
__device__ __forceinline__ s8v zfrag() {
    union { int4 i; s8v v; } u; u.i = make_int4(0, 0, 0, 0); return u.v;
}
// LDS-only barrier: global ops (hsb stores, gathers) stay in flight.
__device__ __forceinline__ void bar_lgkm() {
    asm volatile("s_waitcnt lgkmcnt(0)\n\ts_barrier" ::: "memory");
}

// ---------------------------------------------------------------------------
// Precompute x-projections for all 800 vocab words (biases folded in).
// ---------------------------------------------------------------------------
#define PV 8
__global__ __launch_bounds__(256) void prep_xproj(
    const float* __restrict__ emb,
    const float* __restrict__ Wz, const float* __restrict__ bz,
    const float* __restrict__ Wh, const float* __restrict__ bh,
    const float* __restrict__ Wr, const float* __restrict__ br,
    float* __restrict__ xzT, float* __restrict__ xhT, float* __restrict__ xrT)
{
    __shared__ float embL[PV][HD];
    const int j = threadIdx.x;
    const int v0 = blockIdx.x * PV;
    for (int r = 0; r < PV; ++r) embL[r][j] = emb[(v0 + r) * HD + j];
    __syncthreads();

    float az[PV], ah[PV], ar[PV];
#pragma unroll
    for (int r = 0; r < PV; ++r) { az[r] = bz[j]; ah[r] = bh[j]; ar[r] = br[j]; }
    for (int i = 0; i < HD; i += 4) {
        float wz0 = Wz[(i + 0) * HD + j], wz1 = Wz[(i + 1) * HD + j];
        float wz2 = Wz[(i + 2) * HD + j], wz3 = Wz[(i + 3) * HD + j];
        float wh0 = Wh[(i + 0) * HD + j], wh1 = Wh[(i + 1) * HD + j];
        float wh2 = Wh[(i + 2) * HD + j], wh3 = Wh[(i + 3) * HD + j];
        float wr0 = Wr[(i + 0) * HD + j], wr1 = Wr[(i + 1) * HD + j];
        float wr2 = Wr[(i + 2) * HD + j], wr3 = Wr[(i + 3) * HD + j];
#pragma unroll
        for (int r = 0; r < PV; ++r) {
            float4 e = *(const float4*)&embL[r][i];
            az[r] += e.x * wz0 + e.y * wz1 + e.z * wz2 + e.w * wz3;
            ah[r] += e.x * wh0 + e.y * wh1 + e.z * wh2 + e.w * wh3;
            ar[r] += e.x * wr0 + e.y * wr1 + e.z * wr2 + e.w * wr3;
        }
    }
#pragma unroll
    for (int r = 0; r < PV; ++r) {
        xzT[(v0 + r) * HD + j] = az[r];
        xhT[(v0 + r) * HD + j] = ah[r];
        xrT[(v0 + r) * HD + j] = ar[r];
    }
}

// Fused transpose-convert for the three 256x256 GRU matrices.
__global__ __launch_bounds__(256) void tcvt3(
    const float* __restrict__ Wz, const float* __restrict__ Wh,
    const float* __restrict__ Ur,
    unsigned short* __restrict__ WzT, unsigned short* __restrict__ WhT,
    unsigned short* __restrict__ UrT)
{
    const int which = blockIdx.x >> 8, n = blockIdx.x & 255, k = threadIdx.x;
    const float* src = (which == 0) ? (Wz + HD * HD) : (which == 1) ? (Wh + HD * HD) : Ur;
    unsigned short* dst = (which == 0) ? WzT : (which == 1) ? WhT : UrT;
    dst[n * HD + k] = f2bf(src[k * HD + n]);
}

// Fused transpose-convert for head matrices: W1T[256][320], WoT[800][256], UwT[256][576].
__global__ __launch_bounds__(256) void tcvtQ(
    const float* __restrict__ Ww, const float* __restrict__ Wow,
    const float* __restrict__ Uw,
    unsigned short* __restrict__ W1T, unsigned short* __restrict__ WoT,
    unsigned short* __restrict__ UwT)
{
    int b = blockIdx.x;
    if (b < 256) {
        for (int k = threadIdx.x; k < 320; k += 256)
            W1T[b * 320 + k] = f2bf(Ww[k * 256 + b]);
    } else if (b < 1056) {
        int n = b - 256;
        WoT[n * 256 + threadIdx.x] = f2bf(Wow[threadIdx.x * VOC + n]);
    } else {
        int n = b - 1056;
        for (int k = threadIdx.x; k < 576; k += 256)
            UwT[n * 576 + k] = f2bf(Uw[k * 256 + n]);
    }
}

// Fused bf16 casts: embB (800*256) then tvB (512*64).
__global__ __launch_bounds__(256) void cvtE(
    const float* __restrict__ emb, const float* __restrict__ tv,
    unsigned short* __restrict__ embB, unsigned short* __restrict__ tvB)
{
    int idx = blockIdx.x * 256 + threadIdx.x;
    if (idx < VOC * HD) embB[idx] = f2bf(emb[idx]);
    else {
        int i2 = idx - VOC * HD;
        if (i2 < NTREE * LD) tvB[i2] = f2bf(tv[i2]);
    }
}

// ---------------------------------------------------------------------------
// GRU v9 = gru8 + in-wave shuffle finalize, 2 barriers/step.
// 256 wgs x 512 thr (8 waves, 2/SIMD), 2 trees/wg. Wave w owns col-tiles
// 2w,2w+1 of Wz/Wh IN REGISTERS (32 frags = 128 regs); Ur in LDS (128 KB,
// fragment-contiguous). After each MFMA, 4 __shfl + selects move the C values
// (2 trees x 32 cols = 64 = one per lane) to the owner lane
// (tree=lane>>5, col=32w+(lane&31)); finalize is per-lane, no az/ah/ar LDS.
// Every hsb element is stored+reloaded by the SAME thread (fixed (tree,col)),
// so backtrack reads need no cross-thread ordering. 2 lgkm-only barriers/step.
// ---------------------------------------------------------------------------
__global__ __launch_bounds__(512, 2) void gru9(
    const int* __restrict__ wid,
    const float* __restrict__ xzT, const float* __restrict__ xhT,
    const float* __restrict__ xrT,
    const unsigned short* __restrict__ WzT, const unsigned short* __restrict__ WhT,
    const unsigned short* __restrict__ UrT,
    unsigned short* __restrict__ hsb)
{
    __shared__ unsigned short urL[16 * 8 * 64 * 8];   // 128 KB [tile][kt][lane][8]
    __shared__ unsigned short mBL[2][2][HD], armBL[2][2][HD];
    __shared__ int widL[2][NNODE];

    const int tid = threadIdx.x;
    const int wave = tid >> 6, lane = tid & 63;
    const int lq = lane >> 4, ln = lane & 15;
    const int b0 = blockIdx.x * 2;
    const int T0 = 2 * wave, T1 = T0 + 1;
    // finalize ownership: one (tree,col) element per lane
    const int ftree = lane >> 5;                // 0..1
    const int fcol  = wave * 32 + (lane & 31);  // 32 cols per wave
    const int srcl  = lane & 15;                // shuffle source lane
    const bool hi16 = (lane & 16) != 0;         // tile select (col bit 4)
    const bool hi32 = (lane & 32) != 0;         // tree select

    if (tid < 2 * NNODE) widL[tid / NNODE][tid % NNODE] =
        wid[(b0 + tid / NNODE) * NNODE + (tid % NNODE)];

    // one-time: Ur -> LDS fragment-contiguous
#pragma unroll
    for (int s = 0; s < 16; ++s) {
        *(int4*)&urL[((s * 8 + wave) * 64 + lane) * 8] =
            *(const int4*)&UrT[(s * 16 + ln) * HD + wave * 32 + lq * 8];
    }

    // loop-invariant phase-A weight fragments: 32 frags = 128 regs
    s8v wz0[8], wz1[8], wh0[8], wh1[8];
#pragma unroll
    for (int kt = 0; kt < 8; ++kt) {
        const int ko = kt * 32 + lq * 8;
        wz0[kt] = frag(&WzT[(T0 * 16 + ln) * HD + ko]);
        wz1[kt] = frag(&WzT[(T1 * 16 + ln) * HD + ko]);
        wh0[kt] = frag(&WhT[(T0 * 16 + ln) * HD + ko]);
        wh1[kt] = frag(&WhT[(T1 * 16 + ln) * HD + ko]);
    }
    __syncthreads();   // widL + urL visible

    // per-lane gather state for the (ftree,fcol) element, double-buffered
    float cxz, cxh, cxr, chsp = 0.f, me = 0.f;
    float nxz = 0.f, nxh = 0.f, nxr = 0.f, nhsp = 0.f;
    {   // prologue: t=0 (src=0, dst=1)
        const int ws = widL[ftree][0], wd = widL[ftree][1];
        cxz = xzT[ws * HD + fcol];
        cxh = xhT[ws * HD + fcol];
        cxr = xrT[wd * HD + fcol];
    }

#pragma unroll 2
    for (int t = 0; t < TSTEP; ++t) {
        const int par = t & 1, nxt = par ^ 1;
        const bool fwd = t < NFWD;
        const bool hp = (t != 0) && (t != NFWD);

        // ---- prefetch for t+1 (registers only; overlaps MFMA + barriers) ----
        {
            if (t == NFWD)   // this step's hsp (row 45): same-thread store at t=45
                chsp = bfu(hsb[((NFWD - 2) * NTREE + b0 + ftree) * HD + fcol]);
            const int tn = t + 1;
            if (tn < TSTEP) {
                const bool fwdn = tn < NFWD;
                const int un = TSTEP - tn;
                const int srcn = fwdn ? tn : un;
                const int dstn = fwdn ? (tn + 1) : (un - 1);
                const int ws = widL[ftree][srcn], wd = widL[ftree][dstn];
                nxz = xzT[ws * HD + fcol];
                nxh = xhT[ws * HD + fcol];
                nxr = xrT[wd * HD + fcol];
                nhsp = 0.f;
                if (tn > NFWD && dstn > 0)   // same-thread store >=3 steps ago
                    nhsp = bfu(hsb[((dstn - 1) * NTREE + b0 + ftree) * HD + fcol]);
            }
        }

        // ---- phase A MFMA + shuffle redistribute: az, ah ----
        float az = 0.f, ah = 0.f;
        if (hp) {
            f4v cz0 = (f4v){0.f,0.f,0.f,0.f}, cz1 = cz0, ch0 = cz0, ch1 = cz0;
#pragma unroll
            for (int kt = 0; kt < 8; ++kt) {
                const int ko = kt * 32 + lq * 8;
                s8v am = (ln < 2) ? frag(&mBL[par][ln][ko]) : zfrag();
                s8v aa = (ln < 2) ? frag(&armBL[par][ln][ko]) : zfrag();
                cz0 = __builtin_amdgcn_mfma_f32_16x16x32_bf16(am, wz0[kt], cz0, 0, 0, 0);
                cz1 = __builtin_amdgcn_mfma_f32_16x16x32_bf16(am, wz1[kt], cz1, 0, 0, 0);
                ch0 = __builtin_amdgcn_mfma_f32_16x16x32_bf16(aa, wh0[kt], ch0, 0, 0, 0);
                ch1 = __builtin_amdgcn_mfma_f32_16x16x32_bf16(aa, wh1[kt], ch1, 0, 0, 0);
            }
            // C layout: col = lane&15 (lq=0 lanes), row 0/1 = tree 0/1 (regs 0/1)
            float a00 = __shfl(cz0[0], srcl), a01 = __shfl(cz0[1], srcl);
            float a10 = __shfl(cz1[0], srcl), a11 = __shfl(cz1[1], srcl);
            az = hi16 ? (hi32 ? a11 : a10) : (hi32 ? a01 : a00);
            float h00 = __shfl(ch0[0], srcl), h01 = __shfl(ch0[1], srcl);
            float h10 = __shfl(ch1[0], srcl), h11 = __shfl(ch1[1], srcl);
            ah = hi16 ? (hi32 ? h11 : h10) : (hi32 ? h01 : h00);
        }

        // ---- finalize A (per-lane, no LDS crossing) ----
        {
            float azv = cxz, ahv = cxh, sold = 0.f;
            if (hp) { azv += az; ahv += ah; sold = me; }
            float z = sigm_f(azv), mt = tanh_f(ahv);
            me = sold + z * (mt - sold);
            float hv = fwd ? me : (me + chsp);
            hsb[(t * NTREE + b0 + ftree) * HD + fcol] = f2bf(hv);
            mBL[nxt][ftree][fcol] = f2bf(me);
        }
        bar_lgkm();

        // ---- phase B MFMA + shuffle: ar = m_e @ Ur ----
        {
            f4v cr0 = (f4v){0.f,0.f,0.f,0.f}, cr1 = cr0;
#pragma unroll
            for (int kt = 0; kt < 8; ++kt) {
                const int ko = kt * 32 + lq * 8;
                s8v a = (ln < 2) ? frag(&mBL[nxt][ln][ko]) : zfrag();
                s8v b0f = frag(&urL[((T0 * 8 + kt) * 64 + lane) * 8]);
                s8v b1f = frag(&urL[((T1 * 8 + kt) * 64 + lane) * 8]);
                cr0 = __builtin_amdgcn_mfma_f32_16x16x32_bf16(a, b0f, cr0, 0, 0, 0);
                cr1 = __builtin_amdgcn_mfma_f32_16x16x32_bf16(a, b1f, cr1, 0, 0, 0);
            }
            float r00 = __shfl(cr0[0], srcl), r01 = __shfl(cr0[1], srcl);
            float r10 = __shfl(cr1[0], srcl), r11 = __shfl(cr1[1], srcl);
            float ar = hi16 ? (hi32 ? r11 : r10) : (hi32 ? r01 : r00);
            float r = sigm_f(cxr + ar);
            armBL[nxt][ftree][fcol] = f2bf(r * me);
            cxz = nxz; cxh = nxh; cxr = nxr; chsp = nhsp;
        }
        bar_lgkm();
    }
}

// ---------------------------------------------------------------------------
// Q head, MFMA. 768 wgs (48 trow x 16 tree-groups) x 256 thr. 32 rows/wg.
// ---------------------------------------------------------------------------
#define QG 32
__global__ __launch_bounds__(256) void q3(
    const int* __restrict__ wid,
    const unsigned short* __restrict__ tvB,
    const unsigned short* __restrict__ hsb,
    const unsigned short* __restrict__ W1T,
    const unsigned short* __restrict__ WoT,
    const float* __restrict__ Wb,
    const float* __restrict__ Wob,
    float* __restrict__ acc)
{
    __shared__ unsigned short X1L[QG][328];
    __shared__ unsigned short hidL[QG][264];
    __shared__ int tgts[QG];
    __shared__ float wred[4][QG][4];
    const int tid = threadIdx.x;
    const int wave = tid >> 6, lane = tid & 63;
    const int lq = lane >> 4, ln = lane & 15;
    const int trow = blockIdx.x >> 4;
    const int b0 = (blockIdx.x & 15) * QG;

    if (tid < QG) tgts[tid] = wid[(b0 + tid) * NNODE + trow];
    if (trow == 0) {
        int4 z = make_int4(0, 0, 0, 0);
        for (int idx = tid; idx < QG * 32; idx += 256) {
            int m = idx >> 5, c = idx & 31;
            *(int4*)&X1L[m][c * 8] = z;
        }
    } else {
        const unsigned short* hrow = hsb + (size_t)(trow - 1) * NTREE * HD;
        for (int idx = tid; idx < QG * 32; idx += 256) {
            int m = idx >> 5, c = idx & 31;
            *(int4*)&X1L[m][c * 8] = *(const int4*)&hrow[(b0 + m) * HD + c * 8];
        }
    }
    for (int idx = tid; idx < QG * 8; idx += 256) {
        int m = idx >> 3, c = idx & 7;
        *(int4*)&X1L[m][256 + c * 8] = *(const int4*)&tvB[(b0 + m) * LD + c * 8];
    }
    __syncthreads();

    f4v acc1[2][4];
#pragma unroll
    for (int mt = 0; mt < 2; ++mt)
#pragma unroll
        for (int nt = 0; nt < 4; ++nt) acc1[mt][nt] = (f4v){0.f, 0.f, 0.f, 0.f};
#pragma unroll
    for (int kt = 0; kt < 10; ++kt) {
        s8v a0 = frag(&X1L[ln][kt * 32 + lq * 8]);
        s8v a1 = frag(&X1L[16 + ln][kt * 32 + lq * 8]);
#pragma unroll
        for (int nt = 0; nt < 4; ++nt) {
            int n = wave * 64 + nt * 16 + ln;
            s8v b = frag(&W1T[n * 320 + kt * 32 + lq * 8]);
            acc1[0][nt] = __builtin_amdgcn_mfma_f32_16x16x32_bf16(a0, b, acc1[0][nt], 0, 0, 0);
            acc1[1][nt] = __builtin_amdgcn_mfma_f32_16x16x32_bf16(a1, b, acc1[1][nt], 0, 0, 0);
        }
    }
#pragma unroll
    for (int nt = 0; nt < 4; ++nt) {
        int col = wave * 64 + nt * 16 + ln;
        float wb = Wb[col];
#pragma unroll
        for (int mt = 0; mt < 2; ++mt)
#pragma unroll
            for (int r = 0; r < 4; ++r)
                hidL[mt * 16 + lq * 4 + r][col] = f2bf(fmaxf(acc1[mt][nt][r] + wb, 0.f));
    }
    __syncthreads();

    int rt[2][4];
#pragma unroll
    for (int mt = 0; mt < 2; ++mt)
#pragma unroll
        for (int r = 0; r < 4; ++r) rt[mt][r] = tgts[mt * 16 + lq * 4 + r];
    float mx[2][4], ls[2][4], tg[2][4]; int am[2][4];
#pragma unroll
    for (int mt = 0; mt < 2; ++mt)
#pragma unroll
        for (int r = 0; r < 4; ++r) { mx[mt][r] = -1e30f; ls[mt][r] = 0.f; tg[mt][r] = 0.f; am[mt][r] = 1 << 30; }

    for (int nt = wave; nt < 50; nt += 4) {
        int n = nt * 16 + ln;
        const unsigned short* wrow = WoT + n * 256;
        f4v a2[2];
        a2[0] = (f4v){0.f, 0.f, 0.f, 0.f}; a2[1] = (f4v){0.f, 0.f, 0.f, 0.f};
#pragma unroll
        for (int kt = 0; kt < 8; ++kt) {
            s8v a0 = frag(&hidL[ln][kt * 32 + lq * 8]);
            s8v a1 = frag(&hidL[16 + ln][kt * 32 + lq * 8]);
            s8v b = frag(&wrow[kt * 32 + lq * 8]);
            a2[0] = __builtin_amdgcn_mfma_f32_16x16x32_bf16(a0, b, a2[0], 0, 0, 0);
            a2[1] = __builtin_amdgcn_mfma_f32_16x16x32_bf16(a1, b, a2[1], 0, 0, 0);
        }
        float bias = Wob[n];
#pragma unroll
        for (int mt = 0; mt < 2; ++mt)
#pragma unroll
            for (int r = 0; r < 4; ++r) {
                float v = a2[mt][r] + bias;
                if (n == rt[mt][r]) tg[mt][r] = v;
                float nm = fmaxf(mx[mt][r], v);
                ls[mt][r] = ls[mt][r] * __expf(mx[mt][r] - nm) + __expf(v - nm);
                if (v > mx[mt][r]) am[mt][r] = n;
                mx[mt][r] = nm;
            }
    }

#pragma unroll
    for (int s = 1; s < 16; s <<= 1) {
#pragma unroll
        for (int mt = 0; mt < 2; ++mt)
#pragma unroll
            for (int r = 0; r < 4; ++r) {
                float mo = __shfl_xor(mx[mt][r], s);
                float lo = __shfl_xor(ls[mt][r], s);
                int   ao = __shfl_xor(am[mt][r], s);
                float to = __shfl_xor(tg[mt][r], s);
                tg[mt][r] += to;
                float nm = fmaxf(mx[mt][r], mo);
                ls[mt][r] = ls[mt][r] * __expf(mx[mt][r] - nm) + lo * __expf(mo - nm);
                if (mo > mx[mt][r] || (mo == mx[mt][r] && ao < am[mt][r])) am[mt][r] = ao;
                mx[mt][r] = nm;
            }
    }
    if (ln == 0) {
#pragma unroll
        for (int mt = 0; mt < 2; ++mt)
#pragma unroll
            for (int r = 0; r < 4; ++r) {
                int row = mt * 16 + lq * 4 + r;
                wred[wave][row][0] = mx[mt][r];
                wred[wave][row][1] = ls[mt][r];
                wred[wave][row][2] = __int_as_float(am[mt][r]);
                wred[wave][row][3] = tg[mt][r];
            }
    }
    __syncthreads();

    float lossv = 0.f, corrv = 0.f;
    if (tid < QG) {
        float m_ = -1e30f, l_ = 0.f, t_ = 0.f; int a_ = 1 << 30;
#pragma unroll
        for (int w = 0; w < 4; ++w) {
            float mo = wred[w][tid][0], lo = wred[w][tid][1], to = wred[w][tid][3];
            int ao = __float_as_int(wred[w][tid][2]);
            t_ += to;
            float nm = fmaxf(m_, mo);
            l_ = l_ * __expf(m_ - nm) + lo * __expf(mo - nm);
            if (mo > m_ || (mo == m_ && ao < a_)) a_ = ao;
            m_ = nm;
        }
        lossv = m_ + logf(l_) - t_;
        corrv = (a_ == tgts[tid]) ? 1.f : 0.f;
    }
    if (wave == 0) {
        for (int s = 32; s; s >>= 1) {
            lossv += __shfl_down(lossv, s);
            corrv += __shfl_down(corrv, s);
        }
        if (tid == 0) {
            int slot = blockIdx.x & 255;
            atomicAdd(&acc[0 * 256 + slot], lossv);
            atomicAdd(&acc[2 * 256 + slot], corrv);
        }
    }
}

// ---------------------------------------------------------------------------
// P head, MFMA. 1520 wgs (95 trow x 16 groups) x 256 thr. 32 rows/wg.
// ---------------------------------------------------------------------------
#define PG 32
__global__ __launch_bounds__(256) void p3(
    const int* __restrict__ wid,
    const unsigned short* __restrict__ tvB,
    const unsigned short* __restrict__ embB,
    const unsigned short* __restrict__ hsb,
    const unsigned short* __restrict__ UwT,
    const float* __restrict__ Ub,
    const float* __restrict__ Usw, const float* __restrict__ Usb,
    float* __restrict__ acc)
{
    __shared__ unsigned short XL[PG][584];
    __shared__ int widL[PG];
    __shared__ float wredp[4][PG];
    const int tid = threadIdx.x;
    const int wave = tid >> 6, lane = tid & 63;
    const int lq = lane >> 4, ln = lane & 15;
    const int trow = blockIdx.x >> 4;
    const int b0 = (blockIdx.x & 15) * PG;
    const int node = (trow == 0) ? 0 : ((trow <= NFWD) ? trow : (TSTEP - trow));

    if (tid < PG) widL[tid] = wid[(b0 + tid) * NNODE + node];
    __syncthreads();

    for (int idx = tid; idx < PG * 32; idx += 256) {
        int m = idx >> 5, c = idx & 31;
        *(int4*)&XL[m][c * 8] = *(const int4*)&embB[widL[m] * HD + c * 8];
    }
    if (trow == 0) {
        int4 z = make_int4(0, 0, 0, 0);
        for (int idx = tid; idx < PG * 32; idx += 256) {
            int m = idx >> 5, c = idx & 31;
            *(int4*)&XL[m][256 + c * 8] = z;
        }
    } else {
        const unsigned short* hrow = hsb + (size_t)(trow - 1) * NTREE * HD;
        for (int idx = tid; idx < PG * 32; idx += 256) {
            int m = idx >> 5, c = idx & 31;
            *(int4*)&XL[m][256 + c * 8] = *(const int4*)&hrow[(b0 + m) * HD + c * 8];
        }
    }
    for (int idx = tid; idx < PG * 8; idx += 256) {
        int m = idx >> 3, c = idx & 7;
        *(int4*)&XL[m][512 + c * 8] = *(const int4*)&tvB[(b0 + m) * LD + c * 8];
    }
    __syncthreads();

    f4v a1[2][4];
#pragma unroll
    for (int mt = 0; mt < 2; ++mt)
#pragma unroll
        for (int nt = 0; nt < 4; ++nt) a1[mt][nt] = (f4v){0.f, 0.f, 0.f, 0.f};
    for (int kt = 0; kt < 18; ++kt) {
        s8v a0 = frag(&XL[ln][kt * 32 + lq * 8]);
        s8v am_ = frag(&XL[16 + ln][kt * 32 + lq * 8]);
#pragma unroll
        for (int nt = 0; nt < 4; ++nt) {
            int n = wave * 64 + nt * 16 + ln;
            s8v b = frag(&UwT[n * 576 + kt * 32 + lq * 8]);
            a1[0][nt] = __builtin_amdgcn_mfma_f32_16x16x32_bf16(a0, b, a1[0][nt], 0, 0, 0);
            a1[1][nt] = __builtin_amdgcn_mfma_f32_16x16x32_bf16(am_, b, a1[1][nt], 0, 0, 0);
        }
    }
    float part[2][4] = {{0, 0, 0, 0}, {0, 0, 0, 0}};
#pragma unroll
    for (int nt = 0; nt < 4; ++nt) {
        int n = wave * 64 + nt * 16 + ln;
        float ub = Ub[n], us = Usw[n];
#pragma unroll
        for (int mt = 0; mt < 2; ++mt)
#pragma unroll
            for (int r = 0; r < 4; ++r)
                part[mt][r] += fmaxf(a1[mt][nt][r] + ub, 0.f) * us;
    }
#pragma unroll
    for (int s = 1; s < 16; s <<= 1) {
#pragma unroll
        for (int mt = 0; mt < 2; ++mt)
#pragma unroll
            for (int r = 0; r < 4; ++r)
                part[mt][r] += __shfl_xor(part[mt][r], s);
    }
    if (ln == 0) {
#pragma unroll
        for (int mt = 0; mt < 2; ++mt)
#pragma unroll
            for (int r = 0; r < 4; ++r)
                wredp[wave][mt * 16 + lq * 4 + r] = part[mt][r];
    }
    __syncthreads();

    float lossv = 0.f, corrv = 0.f;
    if (tid < PG) {
        float p = wredp[0][tid] + wredp[1][tid] + wredp[2][tid] + wredp[3][tid] + Usb[0];
        float tgt = (trow < NFWD) ? 1.f : 0.f;
        lossv = fmaxf(p, 0.f) - p * tgt + log1pf(expf(-fabsf(p)));
        corrv = (((p > 0.f) ? 1 : 0) == ((trow < NFWD) ? 1 : 0)) ? 1.f : 0.f;
    }
    if (wave == 0) {
        for (int s = 32; s; s >>= 1) {
            lossv += __shfl_down(lossv, s);
            corrv += __shfl_down(corrv, s);
        }
        if (tid == 0) {
            int slot = blockIdx.x & 255;
            atomicAdd(&acc[1 * 256 + slot], lossv);
            atomicAdd(&acc[3 * 256 + slot], corrv);
        }
    }
}

__global__ void init_kernel(float* __restrict__ acc) {
    acc[threadIdx.x] = 0.f;   // 1024 slots
}

__global__ void fin_kernel(const float* __restrict__ acc, float* __restrict__ out) {
    const int tid = threadIdx.x;
    const int c = tid >> 6, lane = tid & 63;
    float v = 0.f;
    for (int i = lane; i < 256; i += 64) v += acc[c * 256 + i];
    for (int s = 32; s; s >>= 1) v += __shfl_down(v, s);
    if (lane == 0) {
        const float sc[4] = {1.f / 512.f, 1.f / 512.f, 1.f / 24576.f, 1.f / 48640.f};
        out[c] = v * sc[c];
    }
}

extern "C" void kernel_launch(void* const* d_in, const int* in_sizes, int n_in,
                              void* d_out, int out_size, void* d_ws, size_t ws_size,
                              hipStream_t stream) {
    const int*   wid  = (const int*)  d_in[12];
    const float* tv   = (const float*)d_in[13];
    const float* emb  = (const float*)d_in[14];
    const float* Wz   = (const float*)d_in[15];
    const float* bz   = (const float*)d_in[16];
    const float* Wr   = (const float*)d_in[17];
    const float* Ur   = (const float*)d_in[18];
    const float* br   = (const float*)d_in[19];
    const float* Wh   = (const float*)d_in[20];
    const float* bh   = (const float*)d_in[21];
    const float* Ww   = (const float*)d_in[22];
    const float* Wb   = (const float*)d_in[23];
    const float* Uw   = (const float*)d_in[24];
    const float* Ubias= (const float*)d_in[25];
    const float* Wow  = (const float*)d_in[26];
    const float* Wob  = (const float*)d_in[27];
    const float* Usw  = (const float*)d_in[28];
    const float* Usb  = (const float*)d_in[29];

    char* w = (char*)d_ws;
    float* accb = (float*)w;                                 // 4 KB
    float* xzT  = (float*)(w + 4096);                        // 800*256 f32
    float* xhT  = (float*)(w + 823296);
    float* xrT  = (float*)(w + 1642496);
    unsigned short* WzT2 = (unsigned short*)(w + 2461696);   // [256 n][256 k] bf16
    unsigned short* WhT2 = (unsigned short*)(w + 2592768);
    unsigned short* UrT2 = (unsigned short*)(w + 2723840);
    unsigned short* hsb  = (unsigned short*)(w + 2854912);   // 94*512*256 bf16
    unsigned short* W1T  = (unsigned short*)(w + 27496448);  // [256][320]
    unsigned short* WoT  = (unsigned short*)(w + 27660288);  // [800][256]
    unsigned short* UwT  = (unsigned short*)(w + 28069888);  // [256][576]
    unsigned short* embB = (unsigned short*)(w + 28364800);  // [800][256]
    unsigned short* tvB  = (unsigned short*)(w + 28774400);  // [512][64]

    init_kernel<<<1, 1024, 0, stream>>>(accb);
    prep_xproj<<<VOC / PV, 256, 0, stream>>>(emb, Wz, bz, Wh, bh, Wr, br, xzT, xhT, xrT);
    tcvt3<<<768, 256, 0, stream>>>(Wz, Wh, Ur, WzT2, WhT2, UrT2);
    tcvtQ<<<1312, 256, 0, stream>>>(Ww, Wow, Uw, W1T, WoT, UwT);
    cvtE<<<(VOC * HD + NTREE * LD + 255) / 256, 256, 0, stream>>>(emb, tv, embB, tvB);
    gru9<<<NTREE / 2, 512, 0, stream>>>(wid, xzT, xhT, xrT, WzT2, WhT2, UrT2, hsb);
    q3<<<48 * 16, 256, 0, stream>>>(wid, tvB, hsb, W1T, WoT, Wb, Wob, accb);
    p3<<<95 * 16, 256, 0, stream>>>(wid, tvB, embB, hsb, UwT, Ubias, Usw, Usb, accb);
    fin_kernel<<<1, 256, 0, stream>>>(accb, (float*)d_out);
}

// Round 11
// 455.252 us; speedup vs baseline: 2.6238x; 1.0384x over previous
//
#include <hip/hip_runtime.h>
#include <math.h>

#define NTREE 512
#define NNODE 48
#define HD 256
#define LD 64
#define VOC 800
#define TSTEP 94
#define NFWD 47

typedef __attribute__((ext_vector_type(8))) short s8v;   // 8 bf16 (4 VGPRs)
typedef __attribute__((ext_vector_type(4))) float f4v;   // 4 fp32 acc

__device__ __forceinline__ float sigm(float x) { return 1.f / (1.f + expf(-x)); }
// fast device transcendentals (v_exp_f32 + v_rcp_f32), GRU-only
__device__ __forceinline__ float sigm_f(float x) {
    return __builtin_amdgcn_rcpf(1.f + __expf(-x));
}
__device__ __forceinline__ float tanh_f(float x) {
    return 1.f - 2.f * __builtin_amdgcn_rcpf(1.f + __expf(2.f * x));
}

__device__ __forceinline__ float bfu(unsigned short u) {
    union { unsigned int i; float f; } c; c.i = ((unsigned int)u) << 16; return c.f;
}
__device__ __forceinline__ unsigned short f2bf(float f) {
    union { float f; unsigned int u; } c; c.f = f;
    return (unsigned short)((c.u + 0x7fffu + ((c.u >> 16) & 1u)) >> 16);
}
__device__ __forceinline__ s8v frag(const unsigned short* p) {
    union { int4 i; s8v v; } u; u.i = *(const int4*)p; return u.v;
}
__device__ __forceinline__ s8v zfrag() {
    union { int4 i; s8v v; } u; u.i = make_int4(0, 0, 0, 0); return u.v;
}
// Opaque register pin: compiler cannot rematerialize v from memory after this.
__device__ __forceinline__ void pin(s8v& v) {
    asm volatile("" : "+v"(v));
}
// LDS-only barrier: global ops (hsb stores, gathers) stay in flight.
__device__ __forceinline__ void bar_lgkm() {
    asm volatile("s_waitcnt lgkmcnt(0)\n\ts_barrier" ::: "memory");
}

// ---------------------------------------------------------------------------
// Precompute x-projections for all 800 vocab words (biases folded in).
// ---------------------------------------------------------------------------
#define PV 8
__global__ __launch_bounds__(256) void prep_xproj(
    const float* __restrict__ emb,
    const float* __restrict__ Wz, const float* __restrict__ bz,
    const float* __restrict__ Wh, const float* __restrict__ bh,
    const float* __restrict__ Wr, const float* __restrict__ br,
    float* __restrict__ xzT, float* __restrict__ xhT, float* __restrict__ xrT)
{
    __shared__ float embL[PV][HD];
    const int j = threadIdx.x;
    const int v0 = blockIdx.x * PV;
    for (int r = 0; r < PV; ++r) embL[r][j] = emb[(v0 + r) * HD + j];
    __syncthreads();

    float az[PV], ah[PV], ar[PV];
#pragma unroll
    for (int r = 0; r < PV; ++r) { az[r] = bz[j]; ah[r] = bh[j]; ar[r] = br[j]; }
    for (int i = 0; i < HD; i += 4) {
        float wz0 = Wz[(i + 0) * HD + j], wz1 = Wz[(i + 1) * HD + j];
        float wz2 = Wz[(i + 2) * HD + j], wz3 = Wz[(i + 3) * HD + j];
        float wh0 = Wh[(i + 0) * HD + j], wh1 = Wh[(i + 1) * HD + j];
        float wh2 = Wh[(i + 2) * HD + j], wh3 = Wh[(i + 3) * HD + j];
        float wr0 = Wr[(i + 0) * HD + j], wr1 = Wr[(i + 1) * HD + j];
        float wr2 = Wr[(i + 2) * HD + j], wr3 = Wr[(i + 3) * HD + j];
#pragma unroll
        for (int r = 0; r < PV; ++r) {
            float4 e = *(const float4*)&embL[r][i];
            az[r] += e.x * wz0 + e.y * wz1 + e.z * wz2 + e.w * wz3;
            ah[r] += e.x * wh0 + e.y * wh1 + e.z * wh2 + e.w * wh3;
            ar[r] += e.x * wr0 + e.y * wr1 + e.z * wr2 + e.w * wr3;
        }
    }
#pragma unroll
    for (int r = 0; r < PV; ++r) {
        xzT[(v0 + r) * HD + j] = az[r];
        xhT[(v0 + r) * HD + j] = ah[r];
        xrT[(v0 + r) * HD + j] = ar[r];
    }
}

// Fused transpose-convert for the three 256x256 GRU matrices.
__global__ __launch_bounds__(256) void tcvt3(
    const float* __restrict__ Wz, const float* __restrict__ Wh,
    const float* __restrict__ Ur,
    unsigned short* __restrict__ WzT, unsigned short* __restrict__ WhT,
    unsigned short* __restrict__ UrT)
{
    const int which = blockIdx.x >> 8, n = blockIdx.x & 255, k = threadIdx.x;
    const float* src = (which == 0) ? (Wz + HD * HD) : (which == 1) ? (Wh + HD * HD) : Ur;
    unsigned short* dst = (which == 0) ? WzT : (which == 1) ? WhT : UrT;
    dst[n * HD + k] = f2bf(src[k * HD + n]);
}

// Fused transpose-convert for head matrices: W1T[256][320], WoT[800][256], UwT[256][576].
__global__ __launch_bounds__(256) void tcvtQ(
    const float* __restrict__ Ww, const float* __restrict__ Wow,
    const float* __restrict__ Uw,
    unsigned short* __restrict__ W1T, unsigned short* __restrict__ WoT,
    unsigned short* __restrict__ UwT)
{
    int b = blockIdx.x;
    if (b < 256) {
        for (int k = threadIdx.x; k < 320; k += 256)
            W1T[b * 320 + k] = f2bf(Ww[k * 256 + b]);
    } else if (b < 1056) {
        int n = b - 256;
        WoT[n * 256 + threadIdx.x] = f2bf(Wow[threadIdx.x * VOC + n]);
    } else {
        int n = b - 1056;
        for (int k = threadIdx.x; k < 576; k += 256)
            UwT[n * 576 + k] = f2bf(Uw[k * 256 + n]);
    }
}

// Fused bf16 casts: embB (800*256) then tvB (512*64).
__global__ __launch_bounds__(256) void cvtE(
    const float* __restrict__ emb, const float* __restrict__ tv,
    unsigned short* __restrict__ embB, unsigned short* __restrict__ tvB)
{
    int idx = blockIdx.x * 256 + threadIdx.x;
    if (idx < VOC * HD) embB[idx] = f2bf(emb[idx]);
    else {
        int i2 = idx - VOC * HD;
        if (i2 < NTREE * LD) tvB[i2] = f2bf(tv[i2]);
    }
}

// ---------------------------------------------------------------------------
// GRU v10 = gru9 + PINNED weight fragments. 256 wgs x 512 thr (8 waves),
// 2 trees/wg. Wave w owns col-tiles 2w,2w+1 of Wz/Wh in VGPRs, pinned with
// an opaque asm barrier so the compiler CANNOT rematerialize the loads inside
// the t-loop (gru4..gru9 all silently reloaded from L2 every step --
// VGPR_Count 92..100 proved it). Ur in LDS fragment-contiguous (128 KB).
// Shuffle-redistributed finalize, 2 lgkm-only barriers/step.
// ---------------------------------------------------------------------------
__global__ __launch_bounds__(512, 2) void gru10(
    const int* __restrict__ wid,
    const float* __restrict__ xzT, const float* __restrict__ xhT,
    const float* __restrict__ xrT,
    const unsigned short* __restrict__ WzT, const unsigned short* __restrict__ WhT,
    const unsigned short* __restrict__ UrT,
    unsigned short* __restrict__ hsb)
{
    __shared__ unsigned short urL[16 * 8 * 64 * 8];   // 128 KB [tile][kt][lane][8]
    __shared__ unsigned short mBL[2][2][HD], armBL[2][2][HD];
    __shared__ int widL[2][NNODE];

    const int tid = threadIdx.x;
    const int wave = tid >> 6, lane = tid & 63;
    const int lq = lane >> 4, ln = lane & 15;
    const int b0 = blockIdx.x * 2;
    const int T0 = 2 * wave, T1 = T0 + 1;
    // finalize ownership: one (tree,col) element per lane
    const int ftree = lane >> 5;                // 0..1
    const int fcol  = wave * 32 + (lane & 31);  // 32 cols per wave
    const int srcl  = lane & 15;                // shuffle source lane
    const bool hi16 = (lane & 16) != 0;         // tile select (col bit 4)
    const bool hi32 = (lane & 32) != 0;         // tree select

    if (tid < 2 * NNODE) widL[tid / NNODE][tid % NNODE] =
        wid[(b0 + tid / NNODE) * NNODE + (tid % NNODE)];

    // one-time: Ur -> LDS fragment-contiguous
#pragma unroll
    for (int s = 0; s < 16; ++s) {
        *(int4*)&urL[((s * 8 + wave) * 64 + lane) * 8] =
            *(const int4*)&UrT[(s * 16 + ln) * HD + wave * 32 + lq * 8];
    }

    // loop-invariant phase-A weight fragments: 32 frags = 128 regs, PINNED
    s8v wz0[8], wz1[8], wh0[8], wh1[8];
#pragma unroll
    for (int kt = 0; kt < 8; ++kt) {
        const int ko = kt * 32 + lq * 8;
        wz0[kt] = frag(&WzT[(T0 * 16 + ln) * HD + ko]);
        wz1[kt] = frag(&WzT[(T1 * 16 + ln) * HD + ko]);
        wh0[kt] = frag(&WhT[(T0 * 16 + ln) * HD + ko]);
        wh1[kt] = frag(&WhT[(T1 * 16 + ln) * HD + ko]);
    }
#pragma unroll
    for (int kt = 0; kt < 8; ++kt) {
        pin(wz0[kt]); pin(wz1[kt]); pin(wh0[kt]); pin(wh1[kt]);
    }
    __syncthreads();   // widL + urL visible

    // per-lane gather state for the (ftree,fcol) element, double-buffered
    float cxz, cxh, cxr, chsp = 0.f, me = 0.f;
    float nxz = 0.f, nxh = 0.f, nxr = 0.f, nhsp = 0.f;
    {   // prologue: t=0 (src=0, dst=1)
        const int ws = widL[ftree][0], wd = widL[ftree][1];
        cxz = xzT[ws * HD + fcol];
        cxh = xhT[ws * HD + fcol];
        cxr = xrT[wd * HD + fcol];
    }

#pragma unroll 2
    for (int t = 0; t < TSTEP; ++t) {
        const int par = t & 1, nxt = par ^ 1;
        const bool fwd = t < NFWD;
        const bool hp = (t != 0) && (t != NFWD);

        // ---- prefetch for t+1 (registers only; overlaps MFMA + barriers) ----
        {
            if (t == NFWD)   // this step's hsp (row 45): same-thread store at t=45
                chsp = bfu(hsb[((NFWD - 2) * NTREE + b0 + ftree) * HD + fcol]);
            const int tn = t + 1;
            if (tn < TSTEP) {
                const bool fwdn = tn < NFWD;
                const int un = TSTEP - tn;
                const int srcn = fwdn ? tn : un;
                const int dstn = fwdn ? (tn + 1) : (un - 1);
                const int ws = widL[ftree][srcn], wd = widL[ftree][dstn];
                nxz = xzT[ws * HD + fcol];
                nxh = xhT[ws * HD + fcol];
                nxr = xrT[wd * HD + fcol];
                nhsp = 0.f;
                if (tn > NFWD && dstn > 0)   // same-thread store >=3 steps ago
                    nhsp = bfu(hsb[((dstn - 1) * NTREE + b0 + ftree) * HD + fcol]);
            }
        }

        // ---- phase A MFMA + shuffle redistribute: az, ah ----
        float az = 0.f, ah = 0.f;
        if (hp) {
            f4v cz0 = (f4v){0.f,0.f,0.f,0.f}, cz1 = cz0, ch0 = cz0, ch1 = cz0;
#pragma unroll
            for (int kt = 0; kt < 8; ++kt) {
                const int ko = kt * 32 + lq * 8;
                s8v am = (ln < 2) ? frag(&mBL[par][ln][ko]) : zfrag();
                s8v aa = (ln < 2) ? frag(&armBL[par][ln][ko]) : zfrag();
                cz0 = __builtin_amdgcn_mfma_f32_16x16x32_bf16(am, wz0[kt], cz0, 0, 0, 0);
                cz1 = __builtin_amdgcn_mfma_f32_16x16x32_bf16(am, wz1[kt], cz1, 0, 0, 0);
                ch0 = __builtin_amdgcn_mfma_f32_16x16x32_bf16(aa, wh0[kt], ch0, 0, 0, 0);
                ch1 = __builtin_amdgcn_mfma_f32_16x16x32_bf16(aa, wh1[kt], ch1, 0, 0, 0);
            }
            // C layout: col = lane&15 (lq=0 lanes), row 0/1 = tree 0/1 (regs 0/1)
            float a00 = __shfl(cz0[0], srcl), a01 = __shfl(cz0[1], srcl);
            float a10 = __shfl(cz1[0], srcl), a11 = __shfl(cz1[1], srcl);
            az = hi16 ? (hi32 ? a11 : a10) : (hi32 ? a01 : a00);
            float h00 = __shfl(ch0[0], srcl), h01 = __shfl(ch0[1], srcl);
            float h10 = __shfl(ch1[0], srcl), h11 = __shfl(ch1[1], srcl);
            ah = hi16 ? (hi32 ? h11 : h10) : (hi32 ? h01 : h00);
        }

        // ---- finalize A (per-lane, no LDS crossing) ----
        {
            float azv = cxz, ahv = cxh, sold = 0.f;
            if (hp) { azv += az; ahv += ah; sold = me; }
            float z = sigm_f(azv), mt = tanh_f(ahv);
            me = sold + z * (mt - sold);
            float hv = fwd ? me : (me + chsp);
            hsb[(t * NTREE + b0 + ftree) * HD + fcol] = f2bf(hv);
            mBL[nxt][ftree][fcol] = f2bf(me);
        }
        bar_lgkm();

        // ---- phase B MFMA + shuffle: ar = m_e @ Ur ----
        {
            f4v cr0 = (f4v){0.f,0.f,0.f,0.f}, cr1 = cr0;
#pragma unroll
            for (int kt = 0; kt < 8; ++kt) {
                const int ko = kt * 32 + lq * 8;
                s8v a = (ln < 2) ? frag(&mBL[nxt][ln][ko]) : zfrag();
                s8v b0f = frag(&urL[((T0 * 8 + kt) * 64 + lane) * 8]);
                s8v b1f = frag(&urL[((T1 * 8 + kt) * 64 + lane) * 8]);
                cr0 = __builtin_amdgcn_mfma_f32_16x16x32_bf16(a, b0f, cr0, 0, 0, 0);
                cr1 = __builtin_amdgcn_mfma_f32_16x16x32_bf16(a, b1f, cr1, 0, 0, 0);
            }
            float r00 = __shfl(cr0[0], srcl), r01 = __shfl(cr0[1], srcl);
            float r10 = __shfl(cr1[0], srcl), r11 = __shfl(cr1[1], srcl);
            float ar = hi16 ? (hi32 ? r11 : r10) : (hi32 ? r01 : r00);
            float r = sigm_f(cxr + ar);
            armBL[nxt][ftree][fcol] = f2bf(r * me);
            cxz = nxz; cxh = nxh; cxr = nxr; chsp = nhsp;
        }
        bar_lgkm();
    }
}

// ---------------------------------------------------------------------------
// Fused heads: blocks [0,768) = Q head, [768, 768+1520) = P head.
// LDS is a union (max ~40 KB) so occupancy matches the separate kernels.
// ---------------------------------------------------------------------------
#define QG 32
#define PG 32
struct QSmem {
    unsigned short X1L[QG][328];
    unsigned short hidL[QG][264];
    int tgts[QG];
    float wred[4][QG][4];
};
struct PSmem {
    unsigned short XL[PG][584];
    int widL[PG];
    float wredp[4][PG];
};

__global__ __launch_bounds__(256) void heads(
    const int* __restrict__ wid,
    const unsigned short* __restrict__ tvB,
    const unsigned short* __restrict__ embB,
    const unsigned short* __restrict__ hsb,
    const unsigned short* __restrict__ W1T,
    const unsigned short* __restrict__ WoT,
    const unsigned short* __restrict__ UwT,
    const float* __restrict__ Wb, const float* __restrict__ Wob,
    const float* __restrict__ Ub,
    const float* __restrict__ Usw, const float* __restrict__ Usb,
    float* __restrict__ acc)
{
    __shared__ __align__(16) char smem[sizeof(QSmem) > sizeof(PSmem) ? sizeof(QSmem) : sizeof(PSmem)];
    const int tid = threadIdx.x;
    const int wave = tid >> 6, lane = tid & 63;
    const int lq = lane >> 4, ln = lane & 15;

    if (blockIdx.x < 768) {
        // ================= Q head =================
        QSmem& S = *(QSmem*)smem;
        const int trow = blockIdx.x >> 4;
        const int b0 = (blockIdx.x & 15) * QG;

        if (tid < QG) S.tgts[tid] = wid[(b0 + tid) * NNODE + trow];
        if (trow == 0) {
            int4 z = make_int4(0, 0, 0, 0);
            for (int idx = tid; idx < QG * 32; idx += 256) {
                int m = idx >> 5, c = idx & 31;
                *(int4*)&S.X1L[m][c * 8] = z;
            }
        } else {
            const unsigned short* hrow = hsb + (size_t)(trow - 1) * NTREE * HD;
            for (int idx = tid; idx < QG * 32; idx += 256) {
                int m = idx >> 5, c = idx & 31;
                *(int4*)&S.X1L[m][c * 8] = *(const int4*)&hrow[(b0 + m) * HD + c * 8];
            }
        }
        for (int idx = tid; idx < QG * 8; idx += 256) {
            int m = idx >> 3, c = idx & 7;
            *(int4*)&S.X1L[m][256 + c * 8] = *(const int4*)&tvB[(b0 + m) * LD + c * 8];
        }
        __syncthreads();

        f4v acc1[2][4];
#pragma unroll
        for (int mt = 0; mt < 2; ++mt)
#pragma unroll
            for (int nt = 0; nt < 4; ++nt) acc1[mt][nt] = (f4v){0.f, 0.f, 0.f, 0.f};
#pragma unroll
        for (int kt = 0; kt < 10; ++kt) {
            s8v a0 = frag(&S.X1L[ln][kt * 32 + lq * 8]);
            s8v a1 = frag(&S.X1L[16 + ln][kt * 32 + lq * 8]);
#pragma unroll
            for (int nt = 0; nt < 4; ++nt) {
                int n = wave * 64 + nt * 16 + ln;
                s8v b = frag(&W1T[n * 320 + kt * 32 + lq * 8]);
                acc1[0][nt] = __builtin_amdgcn_mfma_f32_16x16x32_bf16(a0, b, acc1[0][nt], 0, 0, 0);
                acc1[1][nt] = __builtin_amdgcn_mfma_f32_16x16x32_bf16(a1, b, acc1[1][nt], 0, 0, 0);
            }
        }
#pragma unroll
        for (int nt = 0; nt < 4; ++nt) {
            int col = wave * 64 + nt * 16 + ln;
            float wb = Wb[col];
#pragma unroll
            for (int mt = 0; mt < 2; ++mt)
#pragma unroll
                for (int r = 0; r < 4; ++r)
                    S.hidL[mt * 16 + lq * 4 + r][col] = f2bf(fmaxf(acc1[mt][nt][r] + wb, 0.f));
        }
        __syncthreads();

        int rt[2][4];
#pragma unroll
        for (int mt = 0; mt < 2; ++mt)
#pragma unroll
            for (int r = 0; r < 4; ++r) rt[mt][r] = S.tgts[mt * 16 + lq * 4 + r];
        float mx[2][4], ls[2][4], tg[2][4]; int am[2][4];
#pragma unroll
        for (int mt = 0; mt < 2; ++mt)
#pragma unroll
            for (int r = 0; r < 4; ++r) { mx[mt][r] = -1e30f; ls[mt][r] = 0.f; tg[mt][r] = 0.f; am[mt][r] = 1 << 30; }

        for (int nt = wave; nt < 50; nt += 4) {
            int n = nt * 16 + ln;
            const unsigned short* wrow = WoT + n * 256;
            f4v a2[2];
            a2[0] = (f4v){0.f, 0.f, 0.f, 0.f}; a2[1] = (f4v){0.f, 0.f, 0.f, 0.f};
#pragma unroll
            for (int kt = 0; kt < 8; ++kt) {
                s8v a0 = frag(&S.hidL[ln][kt * 32 + lq * 8]);
                s8v a1 = frag(&S.hidL[16 + ln][kt * 32 + lq * 8]);
                s8v b = frag(&wrow[kt * 32 + lq * 8]);
                a2[0] = __builtin_amdgcn_mfma_f32_16x16x32_bf16(a0, b, a2[0], 0, 0, 0);
                a2[1] = __builtin_amdgcn_mfma_f32_16x16x32_bf16(a1, b, a2[1], 0, 0, 0);
            }
            float bias = Wob[n];
#pragma unroll
            for (int mt = 0; mt < 2; ++mt)
#pragma unroll
                for (int r = 0; r < 4; ++r) {
                    float v = a2[mt][r] + bias;
                    if (n == rt[mt][r]) tg[mt][r] = v;
                    float nm = fmaxf(mx[mt][r], v);
                    ls[mt][r] = ls[mt][r] * __expf(mx[mt][r] - nm) + __expf(v - nm);
                    if (v > mx[mt][r]) am[mt][r] = n;
                    mx[mt][r] = nm;
                }
        }

#pragma unroll
        for (int s = 1; s < 16; s <<= 1) {
#pragma unroll
            for (int mt = 0; mt < 2; ++mt)
#pragma unroll
                for (int r = 0; r < 4; ++r) {
                    float mo = __shfl_xor(mx[mt][r], s);
                    float lo = __shfl_xor(ls[mt][r], s);
                    int   ao = __shfl_xor(am[mt][r], s);
                    float to = __shfl_xor(tg[mt][r], s);
                    tg[mt][r] += to;
                    float nm = fmaxf(mx[mt][r], mo);
                    ls[mt][r] = ls[mt][r] * __expf(mx[mt][r] - nm) + lo * __expf(mo - nm);
                    if (mo > mx[mt][r] || (mo == mx[mt][r] && ao < am[mt][r])) am[mt][r] = ao;
                    mx[mt][r] = nm;
                }
        }
        if (ln == 0) {
#pragma unroll
            for (int mt = 0; mt < 2; ++mt)
#pragma unroll
                for (int r = 0; r < 4; ++r) {
                    int row = mt * 16 + lq * 4 + r;
                    S.wred[wave][row][0] = mx[mt][r];
                    S.wred[wave][row][1] = ls[mt][r];
                    S.wred[wave][row][2] = __int_as_float(am[mt][r]);
                    S.wred[wave][row][3] = tg[mt][r];
                }
        }
        __syncthreads();

        float lossv = 0.f, corrv = 0.f;
        if (tid < QG) {
            float m_ = -1e30f, l_ = 0.f, t_ = 0.f; int a_ = 1 << 30;
#pragma unroll
            for (int w = 0; w < 4; ++w) {
                float mo = S.wred[w][tid][0], lo = S.wred[w][tid][1], to = S.wred[w][tid][3];
                int ao = __float_as_int(S.wred[w][tid][2]);
                t_ += to;
                float nm = fmaxf(m_, mo);
                l_ = l_ * __expf(m_ - nm) + lo * __expf(mo - nm);
                if (mo > m_ || (mo == m_ && ao < a_)) a_ = ao;
                m_ = nm;
            }
            lossv = m_ + logf(l_) - t_;
            corrv = (a_ == S.tgts[tid]) ? 1.f : 0.f;
        }
        if (wave == 0) {
            for (int s = 32; s; s >>= 1) {
                lossv += __shfl_down(lossv, s);
                corrv += __shfl_down(corrv, s);
            }
            if (tid == 0) {
                int slot = blockIdx.x & 255;
                atomicAdd(&acc[0 * 256 + slot], lossv);
                atomicAdd(&acc[2 * 256 + slot], corrv);
            }
        }
    } else {
        // ================= P head =================
        PSmem& S = *(PSmem*)smem;
        const int pb = blockIdx.x - 768;
        const int trow = pb >> 4;
        const int b0 = (pb & 15) * PG;
        const int node = (trow == 0) ? 0 : ((trow <= NFWD) ? trow : (TSTEP - trow));

        if (tid < PG) S.widL[tid] = wid[(b0 + tid) * NNODE + node];
        __syncthreads();

        for (int idx = tid; idx < PG * 32; idx += 256) {
            int m = idx >> 5, c = idx & 31;
            *(int4*)&S.XL[m][c * 8] = *(const int4*)&embB[S.widL[m] * HD + c * 8];
        }
        if (trow == 0) {
            int4 z = make_int4(0, 0, 0, 0);
            for (int idx = tid; idx < PG * 32; idx += 256) {
                int m = idx >> 5, c = idx & 31;
                *(int4*)&S.XL[m][256 + c * 8] = z;
            }
        } else {
            const unsigned short* hrow = hsb + (size_t)(trow - 1) * NTREE * HD;
            for (int idx = tid; idx < PG * 32; idx += 256) {
                int m = idx >> 5, c = idx & 31;
                *(int4*)&S.XL[m][256 + c * 8] = *(const int4*)&hrow[(b0 + m) * HD + c * 8];
            }
        }
        for (int idx = tid; idx < PG * 8; idx += 256) {
            int m = idx >> 3, c = idx & 7;
            *(int4*)&S.XL[m][512 + c * 8] = *(const int4*)&tvB[(b0 + m) * LD + c * 8];
        }
        __syncthreads();

        f4v a1[2][4];
#pragma unroll
        for (int mt = 0; mt < 2; ++mt)
#pragma unroll
            for (int nt = 0; nt < 4; ++nt) a1[mt][nt] = (f4v){0.f, 0.f, 0.f, 0.f};
        for (int kt = 0; kt < 18; ++kt) {
            s8v a0 = frag(&S.XL[ln][kt * 32 + lq * 8]);
            s8v am_ = frag(&S.XL[16 + ln][kt * 32 + lq * 8]);
#pragma unroll
            for (int nt = 0; nt < 4; ++nt) {
                int n = wave * 64 + nt * 16 + ln;
                s8v b = frag(&UwT[n * 576 + kt * 32 + lq * 8]);
                a1[0][nt] = __builtin_amdgcn_mfma_f32_16x16x32_bf16(a0, b, a1[0][nt], 0, 0, 0);
                a1[1][nt] = __builtin_amdgcn_mfma_f32_16x16x32_bf16(am_, b, a1[1][nt], 0, 0, 0);
            }
        }
        float part[2][4] = {{0, 0, 0, 0}, {0, 0, 0, 0}};
#pragma unroll
        for (int nt = 0; nt < 4; ++nt) {
            int n = wave * 64 + nt * 16 + ln;
            float ub = Ub[n], us = Usw[n];
#pragma unroll
            for (int mt = 0; mt < 2; ++mt)
#pragma unroll
                for (int r = 0; r < 4; ++r)
                    part[mt][r] += fmaxf(a1[mt][nt][r] + ub, 0.f) * us;
        }
#pragma unroll
        for (int s = 1; s < 16; s <<= 1) {
#pragma unroll
            for (int mt = 0; mt < 2; ++mt)
#pragma unroll
                for (int r = 0; r < 4; ++r)
                    part[mt][r] += __shfl_xor(part[mt][r], s);
        }
        if (ln == 0) {
#pragma unroll
            for (int mt = 0; mt < 2; ++mt)
#pragma unroll
                for (int r = 0; r < 4; ++r)
                    S.wredp[wave][mt * 16 + lq * 4 + r] = part[mt][r];
        }
        __syncthreads();

        float lossv = 0.f, corrv = 0.f;
        if (tid < PG) {
            float p = S.wredp[0][tid] + S.wredp[1][tid] + S.wredp[2][tid] + S.wredp[3][tid] + Usb[0];
            float tgt = (trow < NFWD) ? 1.f : 0.f;
            lossv = fmaxf(p, 0.f) - p * tgt + log1pf(expf(-fabsf(p)));
            corrv = (((p > 0.f) ? 1 : 0) == ((trow < NFWD) ? 1 : 0)) ? 1.f : 0.f;
        }
        if (wave == 0) {
            for (int s = 32; s; s >>= 1) {
                lossv += __shfl_down(lossv, s);
                corrv += __shfl_down(corrv, s);
            }
            if (tid == 0) {
                int slot = blockIdx.x & 255;
                atomicAdd(&acc[1 * 256 + slot], lossv);
                atomicAdd(&acc[3 * 256 + slot], corrv);
            }
        }
    }
}

__global__ void init_kernel(float* __restrict__ acc) {
    acc[threadIdx.x] = 0.f;   // 1024 slots
}

__global__ void fin_kernel(const float* __restrict__ acc, float* __restrict__ out) {
    const int tid = threadIdx.x;
    const int c = tid >> 6, lane = tid & 63;
    float v = 0.f;
    for (int i = lane; i < 256; i += 64) v += acc[c * 256 + i];
    for (int s = 32; s; s >>= 1) v += __shfl_down(v, s);
    if (lane == 0) {
        const float sc[4] = {1.f / 512.f, 1.f / 512.f, 1.f / 24576.f, 1.f / 48640.f};
        out[c] = v * sc[c];
    }
}

extern "C" void kernel_launch(void* const* d_in, const int* in_sizes, int n_in,
                              void* d_out, int out_size, void* d_ws, size_t ws_size,
                              hipStream_t stream) {
    const int*   wid  = (const int*)  d_in[12];
    const float* tv   = (const float*)d_in[13];
    const float* emb  = (const float*)d_in[14];
    const float* Wz   = (const float*)d_in[15];
    const float* bz   = (const float*)d_in[16];
    const float* Wr   = (const float*)d_in[17];
    const float* Ur   = (const float*)d_in[18];
    const float* br   = (const float*)d_in[19];
    const float* Wh   = (const float*)d_in[20];
    const float* bh   = (const float*)d_in[21];
    const float* Ww   = (const float*)d_in[22];
    const float* Wb   = (const float*)d_in[23];
    const float* Uw   = (const float*)d_in[24];
    const float* Ubias= (const float*)d_in[25];
    const float* Wow  = (const float*)d_in[26];
    const float* Wob  = (const float*)d_in[27];
    const float* Usw  = (const float*)d_in[28];
    const float* Usb  = (const float*)d_in[29];

    char* w = (char*)d_ws;
    float* accb = (float*)w;                                 // 4 KB
    float* xzT  = (float*)(w + 4096);                        // 800*256 f32
    float* xhT  = (float*)(w + 823296);
    float* xrT  = (float*)(w + 1642496);
    unsigned short* WzT2 = (unsigned short*)(w + 2461696);   // [256 n][256 k] bf16
    unsigned short* WhT2 = (unsigned short*)(w + 2592768);
    unsigned short* UrT2 = (unsigned short*)(w + 2723840);
    unsigned short* hsb  = (unsigned short*)(w + 2854912);   // 94*512*256 bf16
    unsigned short* W1T  = (unsigned short*)(w + 27496448);  // [256][320]
    unsigned short* WoT  = (unsigned short*)(w + 27660288);  // [800][256]
    unsigned short* UwT  = (unsigned short*)(w + 28069888);  // [256][576]
    unsigned short* embB = (unsigned short*)(w + 28364800);  // [800][256]
    unsigned short* tvB  = (unsigned short*)(w + 28774400);  // [512][64]

    init_kernel<<<1, 1024, 0, stream>>>(accb);
    prep_xproj<<<VOC / PV, 256, 0, stream>>>(emb, Wz, bz, Wh, bh, Wr, br, xzT, xhT, xrT);
    tcvt3<<<768, 256, 0, stream>>>(Wz, Wh, Ur, WzT2, WhT2, UrT2);
    tcvtQ<<<1312, 256, 0, stream>>>(Ww, Wow, Uw, W1T, WoT, UwT);
    cvtE<<<(VOC * HD + NTREE * LD + 255) / 256, 256, 0, stream>>>(emb, tv, embB, tvB);
    gru10<<<NTREE / 2, 512, 0, stream>>>(wid, xzT, xhT, xrT, WzT2, WhT2, UrT2, hsb);
    heads<<<768 + 1520, 256, 0, stream>>>(wid, tvB, embB, hsb, W1T, WoT, UwT,
                                          Wb, Wob, Ubias, Usw, Usb, accb);
    fin_kernel<<<1, 256, 0, stream>>>(accb, (float*)d_out);
}